// Round 13
// baseline (2787.825 us; speedup 1.0000x reference)
//
#include <hip/hip_runtime.h>

#define GLOBAL_AS __attribute__((address_space(1)))
#define LDS_AS __attribute__((address_space(3)))

typedef unsigned short u16;
typedef unsigned int u32;
typedef __attribute__((ext_vector_type(4))) float f32x4;
typedef __attribute__((ext_vector_type(8))) short bf16x8;

// Model dims
#define TT 2048
#define EE 1024
#define NHH 16
#define HDD 64
#define HIDD 2816
#define VV 32000
#define MM 4096   // B*T

__device__ __forceinline__ u16 f2bf(float f) {
  u32 u = __builtin_bit_cast(u32, f);
  u += 0x7fffu + ((u >> 16) & 1u);
  return (u16)(u >> 16);
}
__device__ __forceinline__ float bf2f(u16 v) {
  return __builtin_bit_cast(float, (u32)v << 16);
}

// ---------------- elementwise / staging kernels ----------------

__global__ __launch_bounds__(256) void castbf_k(const float* __restrict__ in,
                                                u16* __restrict__ o, long n4) {
  const long i = (long)blockIdx.x * 256 + threadIdx.x;
  if (i >= n4) return;
  const float4 v = ((const float4*)in)[i];
  ((uint2*)o)[i] = make_uint2((u32)f2bf(v.x) | ((u32)f2bf(v.y) << 16),
                              (u32)f2bf(v.z) | ((u32)f2bf(v.w) << 16));
}

__global__ void ropetab_k(float* __restrict__ cosT, float* __restrict__ sinT) {
  const int t = blockIdx.x, j = threadIdx.x;  // j in [0,32)
  const float inv = powf(10000.0f, -(float)j * (1.0f / 32.0f));
  const float f = (float)t * inv;
  cosT[t * 32 + j] = cosf(f);
  sinT[t * 32 + j] = sinf(f);
}

__global__ __launch_bounds__(256) void embed_k(const int* __restrict__ idx,
                                               const float* __restrict__ temb,
                                               float* __restrict__ x) {
  const int row = blockIdx.x;
  const int id = idx[row];
  ((float4*)(x + (size_t)row * EE))[threadIdx.x] =
      ((const float4*)(temb + (size_t)id * EE))[threadIdx.x];
}

__global__ __launch_bounds__(256) void rmsnorm_k(const float* __restrict__ x,
                                                 const float* __restrict__ w,
                                                 u16* __restrict__ o) {
  __shared__ float red[4];
  const int row = blockIdx.x, tid = threadIdx.x;
  const float4 v = ((const float4*)(x + (size_t)row * EE))[tid];
  float ss = v.x * v.x + v.y * v.y + v.z * v.z + v.w * v.w;
#pragma unroll
  for (int off = 32; off; off >>= 1) ss += __shfl_xor(ss, off, 64);
  if ((tid & 63) == 0) red[tid >> 6] = ss;
  __syncthreads();
  const float inv = rsqrtf((red[0] + red[1] + red[2] + red[3]) * (1.0f / 1024.0f) + 1e-6f);
  const float4 wv = ((const float4*)w)[tid];
  const u32 lo = (u32)f2bf(v.x * inv * wv.x) | ((u32)f2bf(v.y * inv * wv.y) << 16);
  const u32 hi = (u32)f2bf(v.z * inv * wv.z) | ((u32)f2bf(v.w * inv * wv.w) << 16);
  ((uint2*)(o + (size_t)row * EE))[tid] = make_uint2(lo, hi);
}

// ---------------- GEMM engine: 256x128 tile, BK=32, 48KB dbuf, 2 blocks/CU ----------------
// Occupancy-first logits engine. 8 waves as 4(m:64 rows)x2(n:64 cols), acc[4][4],
// launch_bounds(512,4) => 4 waves/SIMD, LDS 48KB => 2 blocks/CU.
// Swizzle fixed to the R2-measured-zero-conflict family at 64B row stride:
// write s(row) = (row>>1)&3 (global-unit pre-XOR), read slot = lg ^ ((l15>>1)&3).
__global__ __launch_bounds__(512, 4) void gemm256x(const u16* __restrict__ A,
                                                   const u16* __restrict__ Bw,
                                                   float* __restrict__ C,
                                                   int N, int K) {
  __shared__ u16 lds[2 * 12288];  // 48 KB: per buf A1 4096 | A2 4096 | B 4096 u16
  const int t = threadIdx.x;
  const int lane = t & 63;
  const int w = t >> 6;
  const int wr = w >> 1;   // 0..3 : 64-row group
  const int wc = w & 1;    // 0..1 : 64-col group
  const int l15 = lane & 15, lg = lane >> 4;
  const int bid = blockIdx.x;
  const int row0 = (bid & 15) << 8;
  const int col0 = (bid >> 4) << 7;
  const int NT = K >> 5;

  // staging: row-within-16 = lane>>2, lds unit = lane&3 holds global unit (lane&3)^((lane>>3)&3)
  const int gsw = (((lane & 3) ^ ((lane >> 3) & 3)) << 3);
  const u16* srcA1 = A + (size_t)(row0 + (w >> 1) * 64 + (w & 1) * 16 + (lane >> 2)) * K + gsw;
  const u16* srcA2 = srcA1 + (size_t)32 * K;
  const u16* srcB = Bw + (size_t)(col0 + w * 16 + (lane >> 2)) * K + gsw;
  const int dA1 = (w >> 1) * 1024 + (w & 1) * 512 + lane * 8;
  const int dB = 8192 + w * 512 + lane * 8;

  // fragment read offsets (R2 family: slot = lg ^ ((row>>1)&3))
  const int usw = ((lg ^ ((l15 >> 1) & 3)) << 3);
  const int abase = wr * 1024 + l15 * 32 + usw;            // + (mi>>1)*4096 + (mi&1)*512
  const int bbase = 8192 + wc * 2048 + l15 * 32 + usw;     // + n*512

  f32x4 acc[4][4] = {};

  auto sA1 = [&](int kt, u16* nb) {
    __builtin_amdgcn_global_load_lds((const GLOBAL_AS void*)(srcA1 + (size_t)kt * 32),
                                     (LDS_AS void*)(nb + dA1), 16, 0, 0);
  };
  auto sA2 = [&](int kt, u16* nb) {
    __builtin_amdgcn_global_load_lds((const GLOBAL_AS void*)(srcA2 + (size_t)kt * 32),
                                     (LDS_AS void*)(nb + dA1 + 4096), 16, 0, 0);
  };
  auto sB = [&](int kt, u16* nb) {
    __builtin_amdgcn_global_load_lds((const GLOBAL_AS void*)(srcB + (size_t)kt * 32),
                                     (LDS_AS void*)(nb + dB), 16, 0, 0);
  };

  // prologue: tile 0 in consumption order (A1, B, A2)
  sA1(0, lds); sB(0, lds); sA2(0, lds);

  for (int kt = 0; kt < NT; ++kt) {
    const bool st = (kt + 1 < NT);
    u16* cb = lds + (kt & 1) * 12288;
    u16* nb = lds + ((kt + 1) & 1) * 12288;
    bf16x8 af[4], bfv[4];

    // ---- ph0: vmcnt(1) proves A1,B(t); read m0-1 + B; stage A1,B(t+1); MFMA m0-1 ----
    asm volatile("s_waitcnt vmcnt(1)" ::: "memory");
    __builtin_amdgcn_s_barrier();
#pragma unroll
    for (int mi = 0; mi < 2; ++mi) af[mi] = *(const bf16x8*)&cb[abase + mi * 512];
#pragma unroll
    for (int n = 0; n < 4; ++n) bfv[n] = *(const bf16x8*)&cb[bbase + n * 512];
    if (st) { sA1(kt + 1, nb); sB(kt + 1, nb); }
    __builtin_amdgcn_s_setprio(1);
#pragma unroll
    for (int mi = 0; mi < 2; ++mi)
#pragma unroll
      for (int n = 0; n < 4; ++n)
        acc[mi][n] = __builtin_amdgcn_mfma_f32_16x16x32_bf16(af[mi], bfv[n], acc[mi][n], 0, 0, 0);
    __builtin_amdgcn_s_setprio(0);

    // ---- ph1: vmcnt(2|0) proves A2(t); read m2-3; stage A2(t+1); MFMA m2-3 ----
    if (st) { asm volatile("s_waitcnt vmcnt(2)" ::: "memory"); }
    else    { asm volatile("s_waitcnt vmcnt(0)" ::: "memory"); }
    __builtin_amdgcn_s_barrier();
#pragma unroll
    for (int mi = 0; mi < 2; ++mi) af[2 + mi] = *(const bf16x8*)&cb[abase + 4096 + mi * 512];
    if (st) sA2(kt + 1, nb);
    __builtin_amdgcn_s_setprio(1);
#pragma unroll
    for (int mi = 0; mi < 2; ++mi)
#pragma unroll
      for (int n = 0; n < 4; ++n)
        acc[2 + mi][n] = __builtin_amdgcn_mfma_f32_16x16x32_bf16(af[2 + mi], bfv[n], acc[2 + mi][n], 0, 0, 0);
    __builtin_amdgcn_s_setprio(0);
  }

#pragma unroll
  for (int m = 0; m < 4; ++m) {
    const int row = row0 + wr * 64 + m * 16 + lg * 4;
#pragma unroll
    for (int n = 0; n < 4; ++n) {
      const int col = col0 + wc * 64 + n * 16 + l15;
#pragma unroll
      for (int r = 0; r < 4; ++r)
        C[(size_t)(row + r) * N + col] = acc[m][n][r];
    }
  }
}

// ---------------- GEMM engine: 128x128, 8 waves (wave-tile 32x64), ring, epilogues ----------------
// Proven R8/R10 ring schedule: 4-buf LDS ring, depth-3 prefetch, counted vmcnt 4/2/0.
// OUTBF: 0 f32 C = acc + R ; 3 rope-split (Q pre-scaled by 0.125*log2e for exp2 softmax).
template <int OUTBF>
__global__ __launch_bounds__(512, 2) void gemm128n(const u16* __restrict__ A,
                                                   const u16* __restrict__ Bw,
                                                   float* __restrict__ C,
                                                   const float* __restrict__ R,
                                                   const float* __restrict__ cosT,
                                                   const float* __restrict__ sinT,
                                                   u16* __restrict__ Qb,
                                                   u16* __restrict__ Kb,
                                                   u16* __restrict__ Vtb,
                                                   int N, int K) {
  __shared__ u16 lds[4 * 8192];  // 64 KB: 4 buffers x (A 128x32 | B 128x32)
  const int t = threadIdx.x;
  const int lane = t & 63;
  const int wid = t >> 6;
  const int wr = wid & 3;    // 0..3 : 32-row group
  const int wc = wid >> 2;   // 0..1 : 64-col group
  const int l15 = lane & 15, lg = lane >> 4;
  const int bid = blockIdx.x;
  const int row0 = (bid & 31) << 7;
  const int col0 = (bid >> 5) << 7;
  const int NT = K >> 5;

  const int rA = t >> 2;  // 0..127
  const int usw = (((t & 3) ^ ((t >> 3) & 3)) << 3);
  const u16* sA = A + (size_t)(row0 + rA) * K + usw;
  const u16* sB = Bw + (size_t)(col0 + rA) * K + usw;
  const int dst = t << 3;  // 0..4095

  const int e8 = ((lg ^ ((l15 >> 1) & 3)) << 3);
  const int aoff = (wr * 32 + l15) * 32 + e8;
  const int boff = 4096 + (wc * 64 + l15) * 32 + e8;

  f32x4 acc[2][4] = {};

  auto stage = [&](int kt) {
    u16* base = &lds[(kt & 3) * 8192];
    const size_t ko = (size_t)kt * 32;
    __builtin_amdgcn_global_load_lds((const GLOBAL_AS void*)(sA + ko),
                                     (LDS_AS void*)(base + dst), 16, 0, 0);
    __builtin_amdgcn_global_load_lds((const GLOBAL_AS void*)(sB + ko),
                                     (LDS_AS void*)(base + 4096 + dst), 16, 0, 0);
  };

  stage(0);
  stage(1);
  stage(2);

  for (int kt = 0; kt < NT; ++kt) {
    const int rem = NT - 1 - kt;
    if (rem >= 2) {
      asm volatile("s_waitcnt vmcnt(4)" ::: "memory");
    } else if (rem == 1) {
      asm volatile("s_waitcnt vmcnt(2)" ::: "memory");
    } else {
      asm volatile("s_waitcnt vmcnt(0)" ::: "memory");
    }
    __builtin_amdgcn_s_barrier();
    if (kt + 3 < NT) stage(kt + 3);
    const u16* base = &lds[(kt & 3) * 8192];
    bf16x8 af[2], bfv[4];
#pragma unroll
    for (int m = 0; m < 2; ++m) af[m] = *(const bf16x8*)&base[aoff + m * 512];
#pragma unroll
    for (int n = 0; n < 4; ++n) bfv[n] = *(const bf16x8*)&base[boff + n * 512];
    __builtin_amdgcn_s_setprio(1);
#pragma unroll
    for (int m = 0; m < 2; ++m)
#pragma unroll
      for (int n = 0; n < 4; ++n)
        acc[m][n] = __builtin_amdgcn_mfma_f32_16x16x32_bf16(af[m], bfv[n], acc[m][n], 0, 0, 0);
    __builtin_amdgcn_s_setprio(0);
  }

  if (OUTBF == 3) {
    // fused RoPE + QKV split. Tile entirely in Q (col0<1024), K, or V region.
    const int reg = col0 >> 10;
    const int fb = col0 & 1023;
#pragma unroll
    for (int m = 0; m < 2; ++m) {
      const int row = row0 + wr * 32 + m * 16 + lg * 4;
      const int b = row >> 11, tbase = row & 2047;
      if (reg < 2) {
        u16* dstp = (reg == 0) ? Qb : Kb;
        // Q pre-scaled by 0.125*log2(e) so attn softmax uses raw v_exp_f32 (2^x).
        const float qs = (reg == 0) ? 0.18033688011112042f : 1.0f;
#pragma unroll
        for (int n = 0; n < 2; ++n) {
          const int f = fb + wc * 64 + n * 16 + l15;
          const int h = f >> 6, j = f & 63;  // j < 32
#pragma unroll
          for (int r = 0; r < 4; ++r) {
            const int tt = tbase + r;
            const float c = cosT[tt * 32 + j], s = sinT[tt * 32 + j];
            const float x1 = acc[m][n][r], x2 = acc[m][n | 2][r];
            const size_t ro = ((size_t)(b * NHH + h) * TT + tt) * HDD + j;
            dstp[ro] = f2bf((x1 * c - x2 * s) * qs);
            dstp[ro + 32] = f2bf((x1 * s + x2 * c) * qs);
          }
        }
      } else {
#pragma unroll
        for (int n = 0; n < 4; ++n) {
          const int f = fb + wc * 64 + n * 16 + l15;
          const int h = f >> 6, j = f & 63;
          ushort4 pk;
          pk.x = f2bf(acc[m][n][0]);
          pk.y = f2bf(acc[m][n][1]);
          pk.z = f2bf(acc[m][n][2]);
          pk.w = f2bf(acc[m][n][3]);
          *(ushort4*)&Vtb[((size_t)(b * NHH + h) * HDD + j) * TT + tbase] = pk;
        }
      }
    }
    return;
  }

#pragma unroll
  for (int m = 0; m < 2; ++m) {
    const int row = row0 + wr * 32 + m * 16 + lg * 4;
#pragma unroll
    for (int n = 0; n < 4; ++n) {
      const int col = col0 + wc * 64 + n * 16 + l15;
#pragma unroll
      for (int r = 0; r < 4; ++r) {
        const size_t o = (size_t)(row + r) * N + col;
        C[o] = acc[m][n][r] + R[o];
      }
    }
  }
}

// ---------------- GEMM engine: dual-B 128x64 (g=A*W1^T, u=A*W2^T, silu fused), ----------------
// R10 ring: 3 bufs x 16KB, depth-2, counted vmcnt 2/0 at phase top, reads after barrier.
__global__ __launch_bounds__(512, 2) void gemm128d(const u16* __restrict__ A,
                                                   const u16* __restrict__ Bg,
                                                   const u16* __restrict__ Bu,
                                                   u16* __restrict__ C16,
                                                   int N, int K) {
  __shared__ u16 lds[3 * 8192];  // 48 KB: 3 bufs x (A 4096 | Bg 2048 | Bu 2048) u16
  const int t = threadIdx.x;
  const int lane = t & 63;
  const int wid = t >> 6;
  const int wr = wid & 3;    // 32-row group
  const int wc = wid >> 2;   // 0..1 : 32-col group
  const int l15 = lane & 15, lg = lane >> 4;
  const int bid = blockIdx.x;
  const int row0 = (bid & 31) << 7;   // 32 row tiles of 128
  const int col0 = (bid >> 5) << 6;   // 64-col tiles
  const int NT = K >> 5;

  const int rA = t >> 2;              // 0..127
  const int usw = (((t & 3) ^ ((t >> 3) & 3)) << 3);
  const u16* sA = A + (size_t)(row0 + rA) * K + usw;
  const int tb = t & 255;
  const int rB = tb >> 2;             // 0..63
  const int uswB = (((tb & 3) ^ ((tb >> 3) & 3)) << 3);
  const u16* sB = ((wid < 4) ? Bg : Bu) + (size_t)(col0 + rB) * K + uswB;
  const int dstA = t << 3;
  const int dstB = 4096 + ((wid < 4) ? 0 : 2048) + (tb << 3);

  const int e8 = ((lg ^ ((l15 >> 1) & 3)) << 3);
  const int aoff = (wr * 32 + l15) * 32 + e8;
  const int goff = 4096 + (wc * 32 + l15) * 32 + e8;
  const int uoff = 6144 + (wc * 32 + l15) * 32 + e8;

  f32x4 ag[2][2] = {}, au[2][2] = {};

  auto stage = [&](int kt, int buf) {
    u16* b = &lds[buf * 8192];
    const size_t ko = (size_t)kt * 32;
    __builtin_amdgcn_global_load_lds((const GLOBAL_AS void*)(sA + ko),
                                     (LDS_AS void*)(b + dstA), 16, 0, 0);
    __builtin_amdgcn_global_load_lds((const GLOBAL_AS void*)(sB + ko),
                                     (LDS_AS void*)(b + dstB), 16, 0, 0);
  };

  stage(0, 0);
  stage(1, 1);

  int cbuf = 0;
  for (int kt = 0; kt < NT; ++kt) {
    if (kt + 1 < NT) {
      asm volatile("s_waitcnt vmcnt(2)" ::: "memory");
    } else {
      asm volatile("s_waitcnt vmcnt(0)" ::: "memory");
    }
    __builtin_amdgcn_s_barrier();
    const int nbuf = (cbuf == 2) ? 0 : cbuf + 1;
    const int sbuf = (nbuf == 2) ? 0 : nbuf + 1;
    if (kt + 2 < NT) stage(kt + 2, sbuf);
    const u16* cb = &lds[cbuf * 8192];
    bf16x8 af[2], bgv[2], buv[2];
#pragma unroll
    for (int m = 0; m < 2; ++m) af[m] = *(const bf16x8*)&cb[aoff + m * 512];
#pragma unroll
    for (int n = 0; n < 2; ++n) {
      bgv[n] = *(const bf16x8*)&cb[goff + n * 512];
      buv[n] = *(const bf16x8*)&cb[uoff + n * 512];
    }
    __builtin_amdgcn_s_setprio(1);
#pragma unroll
    for (int m = 0; m < 2; ++m)
#pragma unroll
      for (int n = 0; n < 2; ++n) {
        ag[m][n] = __builtin_amdgcn_mfma_f32_16x16x32_bf16(af[m], bgv[n], ag[m][n], 0, 0, 0);
        au[m][n] = __builtin_amdgcn_mfma_f32_16x16x32_bf16(af[m], buv[n], au[m][n], 0, 0, 0);
      }
    __builtin_amdgcn_s_setprio(0);
    cbuf = nbuf;
  }

#pragma unroll
  for (int m = 0; m < 2; ++m) {
    const int row = row0 + wr * 32 + m * 16 + lg * 4;
#pragma unroll
    for (int n = 0; n < 2; ++n) {
      const int col = col0 + wc * 32 + n * 16 + l15;
#pragma unroll
      for (int r = 0; r < 4; ++r) {
        const float g = ag[m][n][r];
        const float u = au[m][n][r];
        C16[(size_t)(row + r) * N + col] = f2bf(g / (1.0f + __expf(-g)) * u);
      }
    }
  }
}

// ---------------- attention: 8 waves x 16 q-rows (4 waves/SIMD TLP), no-max exp2 ----------------
// softmax (Q pre-scaled), denominator via MFMA row-sum, P->bf16 via v_cvt_pk,
// causal load-balanced grid. P_lds wave-private, no barriers.
__global__ __launch_bounds__(512) void attn_k(const u16* __restrict__ Q,
                                              const u16* __restrict__ Kc,
                                              const u16* __restrict__ Vt,
                                              u16* __restrict__ O) {
  __shared__ u16 P_lds[8][16][72];
  const int bid = blockIdx.x;           // 512 blocks
  const int bh = bid & 31;
  const int jj = bid >> 5;              // 0..15
  const int qi = (bid < 256) ? jj : 23 - jj;
  const int q0 = qi << 7;
  const int lane = threadIdx.x & 63;
  const int w = threadIdx.x >> 6;       // 0..7
  const int l15 = lane & 15, lg = lane >> 4;
  const int qbase = q0 + w * 16;

  bf16x8 qf[2];
#pragma unroll
  for (int ks = 0; ks < 2; ++ks)
    qf[ks] = *(const bf16x8*)&Q[((size_t)bh * TT + qbase + l15) * HDD + ks * 32 + lg * 8];

  bf16x8 ones;
#pragma unroll
  for (int i = 0; i < 8; ++i) ones[i] = (short)0x3F80;  // bf16 1.0

  f32x4 oacc[4] = {};
  f32x4 lacc = {};

  const int ntile = (q0 + 128) >> 6;
  for (int kt = 0; kt < ntile; ++kt) {
    const int k0 = kt << 6;
    f32x4 s[4];
#pragma unroll
    for (int an = 0; an < 4; ++an) {
      const bf16x8 kf0 = *(const bf16x8*)&Kc[((size_t)bh * TT + k0 + an * 16 + l15) * HDD + lg * 8];
      const bf16x8 kf1 = *(const bf16x8*)&Kc[((size_t)bh * TT + k0 + an * 16 + l15) * HDD + 32 + lg * 8];
      f32x4 z = {0.0f, 0.0f, 0.0f, 0.0f};
      z = __builtin_amdgcn_mfma_f32_16x16x32_bf16(qf[0], kf0, z, 0, 0, 0);
      s[an] = __builtin_amdgcn_mfma_f32_16x16x32_bf16(qf[1], kf1, z, 0, 0, 0);
    }
    // causal mask + 2^x (Q pre-scaled by 0.125*log2e; scores bounded, f32-safe)
    const bool diag = (k0 + 64) > q0;
#pragma unroll
    for (int an = 0; an < 4; ++an)
#pragma unroll
      for (int r = 0; r < 4; ++r) {
        float v = s[an][r];
        if (diag) {
          const int qrow = qbase + lg * 4 + r;
          const int kcol = k0 + an * 16 + l15;
          if (kcol > qrow) v = -1e30f;
        }
        float p;
        asm("v_exp_f32 %0, %1" : "=v"(p) : "v"(v));
        s[an][r] = p;
      }
    // P -> LDS via packed bf16 conversion (wave-private region)
#pragma unroll
    for (int an = 0; an < 4; ++an)
#pragma unroll
      for (int rp = 0; rp < 2; ++rp) {
        u32 pk;
        asm("v_cvt_pk_bf16_f32 %0, %1, %2"
            : "=v"(pk) : "v"(s[an][2 * rp]), "v"(s[an][2 * rp + 1]));
        const int rowb = lg * 4 + 2 * rp;
        P_lds[w][rowb][an * 16 + l15] = (u16)pk;
        P_lds[w][rowb + 1][an * 16 + l15] = (u16)(pk >> 16);
      }
#pragma unroll
    for (int ks = 0; ks < 2; ++ks) {
      const bf16x8 pf = *(const bf16x8*)&P_lds[w][l15][ks * 32 + lg * 8];
      __builtin_amdgcn_s_setprio(1);
#pragma unroll
      for (int dn = 0; dn < 4; ++dn) {
        const bf16x8 vf = *(const bf16x8*)&Vt[((size_t)bh * HDD + dn * 16 + l15) * TT + k0 + ks * 32 + lg * 8];
        oacc[dn] = __builtin_amdgcn_mfma_f32_16x16x32_bf16(pf, vf, oacc[dn], 0, 0, 0);
      }
      lacc = __builtin_amdgcn_mfma_f32_16x16x32_bf16(pf, ones, lacc, 0, 0, 0);
      __builtin_amdgcn_s_setprio(0);
    }
  }
  const int b = bh >> 4, h = bh & 15;
#pragma unroll
  for (int r = 0; r < 4; ++r) {
    const float il = 1.0f / lacc[r];
    const int qrow = qbase + lg * 4 + r;
#pragma unroll
    for (int dn = 0; dn < 4; ++dn)
      O[((size_t)b * TT + qrow) * EE + h * 64 + dn * 16 + l15] = f2bf(oacc[dn][r] * il);
  }
}

// ---------------- host ----------------

extern "C" void kernel_launch(void* const* d_in, const int* in_sizes, int n_in,
                              void* d_out, int out_size, void* d_ws, size_t ws_size,
                              hipStream_t stream) {
  const int* idx = (const int*)d_in[0];
  const float* tok_emb = (const float*)d_in[1];
  const float* qkv_w = (const float*)d_in[2];
  const float* proj_w = (const float*)d_in[3];
  const float* w1 = (const float*)d_in[4];
  const float* w2 = (const float*)d_in[5];
  const float* w3 = (const float*)d_in[6];
  const float* norm1_w = (const float*)d_in[7];
  const float* norm2_w = (const float*)d_in[8];
  const float* norm_f_w = (const float*)d_in[9];
  float* out = (float*)d_out;

  char* ws = (char*)d_ws;
  size_t off = 0;
  auto alloc = [&](size_t bytes) -> void* {
    off = (off + 255) & ~(size_t)255;
    void* p = ws + off;
    off += bytes;
    return p;
  };

  const size_t N_TEMB = (size_t)VV * EE;
  const size_t N_QKVW = (size_t)8 * 3 * EE * EE;
  const size_t N_PROJW = (size_t)8 * EE * EE;
  const size_t N_W1 = (size_t)8 * HIDD * EE;
  const size_t N_W3 = (size_t)8 * EE * HIDD;

  u16* tembbf = (u16*)alloc(N_TEMB * 2);
  u16* qkvwbf = (u16*)alloc(N_QKVW * 2);
  u16* projwbf = (u16*)alloc(N_PROJW * 2);
  u16* w1bf = (u16*)alloc(N_W1 * 2);
  u16* w2bf = (u16*)alloc(N_W1 * 2);
  u16* w3bf = (u16*)alloc(N_W3 * 2);
  float* x = (float*)alloc((size_t)MM * EE * 4);
  u16* h1 = (u16*)alloc((size_t)MM * EE * 2);
  u16* hg = (u16*)alloc((size_t)MM * HIDD * 2);
  u16* qb = (u16*)alloc((size_t)2 * NHH * TT * HDD * 2);
  u16* kb = (u16*)alloc((size_t)2 * NHH * TT * HDD * 2);
  u16* vtb = (u16*)alloc((size_t)2 * NHH * TT * HDD * 2);
  u16* attno = (u16*)alloc((size_t)MM * EE * 2);
  float* cosT = (float*)alloc((size_t)TT * 32 * 4);
  float* sinT = (float*)alloc((size_t)TT * 32 * 4);

  auto cast = [&](const float* src, u16* dst, size_t n) {
    const long n4 = (long)(n / 4);
    castbf_k<<<(int)((n4 + 255) / 256), 256, 0, stream>>>(src, dst, n4);
  };
  cast(tok_emb, tembbf, N_TEMB);
  cast(qkv_w, qkvwbf, N_QKVW);
  cast(proj_w, projwbf, N_PROJW);
  cast(w1, w1bf, N_W1);
  cast(w2, w2bf, N_W1);
  cast(w3, w3bf, N_W3);

  ropetab_k<<<TT, 32, 0, stream>>>(cosT, sinT);
  embed_k<<<MM, 256, 0, stream>>>(idx, tok_emb, x);

  for (int l = 0; l < 8; ++l) {
    rmsnorm_k<<<MM, 256, 0, stream>>>(x, norm1_w + l * EE, h1);
    gemm128n<3><<<dim3(24 * 32), 512, 0, stream>>>(h1, qkvwbf + (size_t)l * 3 * EE * EE,
                                                   nullptr, nullptr,
                                                   cosT, sinT, qb, kb, vtb, 3 * EE, EE);
    attn_k<<<dim3(512), 512, 0, stream>>>(qb, kb, vtb, attno);
    gemm128n<0><<<dim3(8 * 32), 512, 0, stream>>>(attno, projwbf + (size_t)l * EE * EE,
                                                  x, x,
                                                  nullptr, nullptr, nullptr, nullptr, nullptr,
                                                  EE, EE);
    rmsnorm_k<<<MM, 256, 0, stream>>>(x, norm2_w + l * EE, h1);
    gemm128d<<<dim3(44 * 32), 512, 0, stream>>>(h1, w1bf + (size_t)l * HIDD * EE,
                                                w2bf + (size_t)l * HIDD * EE,
                                                hg, HIDD, EE);
    gemm128n<0><<<dim3(8 * 32), 512, 0, stream>>>(hg, w3bf + (size_t)l * EE * HIDD,
                                                  x, x,
                                                  nullptr, nullptr, nullptr, nullptr, nullptr,
                                                  EE, HIDD);
  }
  rmsnorm_k<<<MM, 256, 0, stream>>>(x, norm_f_w, h1);
  // logits: 256x128-tile occupancy engine, 16 row-tiles x 250 col-tiles
  gemm256x<<<dim3(250 * 16), 512, 0, stream>>>(h1, tembbf, out, VV, EE);
}

// Round 14
// 2423.094 us; speedup vs baseline: 1.1505x; 1.1505x over previous
//
#include <hip/hip_runtime.h>

#define GLOBAL_AS __attribute__((address_space(1)))
#define LDS_AS __attribute__((address_space(3)))

typedef unsigned short u16;
typedef unsigned int u32;
typedef __attribute__((ext_vector_type(4))) float f32x4;
typedef __attribute__((ext_vector_type(8))) short bf16x8;

// Model dims
#define TT 2048
#define EE 1024
#define NHH 16
#define HDD 64
#define HIDD 2816
#define VV 32000
#define MM 4096   // B*T

__device__ __forceinline__ u16 f2bf(float f) {
  u32 u = __builtin_bit_cast(u32, f);
  u += 0x7fffu + ((u >> 16) & 1u);
  return (u16)(u >> 16);
}
__device__ __forceinline__ float bf2f(u16 v) {
  return __builtin_bit_cast(float, (u32)v << 16);
}

// ---------------- elementwise / staging kernels ----------------

__global__ __launch_bounds__(256) void castbf_k(const float* __restrict__ in,
                                                u16* __restrict__ o, long n4) {
  const long i = (long)blockIdx.x * 256 + threadIdx.x;
  if (i >= n4) return;
  const float4 v = ((const float4*)in)[i];
  ((uint2*)o)[i] = make_uint2((u32)f2bf(v.x) | ((u32)f2bf(v.y) << 16),
                              (u32)f2bf(v.z) | ((u32)f2bf(v.w) << 16));
}

__global__ void ropetab_k(float* __restrict__ cosT, float* __restrict__ sinT) {
  const int t = blockIdx.x, j = threadIdx.x;  // j in [0,32)
  const float inv = powf(10000.0f, -(float)j * (1.0f / 32.0f));
  const float f = (float)t * inv;
  cosT[t * 32 + j] = cosf(f);
  sinT[t * 32 + j] = sinf(f);
}

__global__ __launch_bounds__(256) void embed_k(const int* __restrict__ idx,
                                               const float* __restrict__ temb,
                                               float* __restrict__ x) {
  const int row = blockIdx.x;
  const int id = idx[row];
  ((float4*)(x + (size_t)row * EE))[threadIdx.x] =
      ((const float4*)(temb + (size_t)id * EE))[threadIdx.x];
}

__global__ __launch_bounds__(256) void rmsnorm_k(const float* __restrict__ x,
                                                 const float* __restrict__ w,
                                                 u16* __restrict__ o) {
  __shared__ float red[4];
  const int row = blockIdx.x, tid = threadIdx.x;
  const float4 v = ((const float4*)(x + (size_t)row * EE))[tid];
  float ss = v.x * v.x + v.y * v.y + v.z * v.z + v.w * v.w;
#pragma unroll
  for (int off = 32; off; off >>= 1) ss += __shfl_xor(ss, off, 64);
  if ((tid & 63) == 0) red[tid >> 6] = ss;
  __syncthreads();
  const float inv = rsqrtf((red[0] + red[1] + red[2] + red[3]) * (1.0f / 1024.0f) + 1e-6f);
  const float4 wv = ((const float4*)w)[tid];
  const u32 lo = (u32)f2bf(v.x * inv * wv.x) | ((u32)f2bf(v.y * inv * wv.y) << 16);
  const u32 hi = (u32)f2bf(v.z * inv * wv.z) | ((u32)f2bf(v.w * inv * wv.w) << 16);
  ((uint2*)(o + (size_t)row * EE))[tid] = make_uint2(lo, hi);
}

// ---------------- GEMM engine: 256x256, BK=64, 4-phase counted-vmcnt dbuf (R5 engine) ----------------
// Used for the logits GEMM only (grid 2000 blocks). Best measured schedule (38% MfmaUtil).
template <int OUTBF>
__global__ __launch_bounds__(512, 2) void gemm256p(const u16* __restrict__ A,
                                                   const u16* __restrict__ Bw,
                                                   float* __restrict__ C,
                                                   u16* __restrict__ C16,
                                                   const u16* __restrict__ G,
                                                   int N, int K) {
  __shared__ u16 lds[2 * 32768];  // 128 KB
  const int t = threadIdx.x;
  const int lane = t & 63;
  const int wid = t >> 6;
  const int wr = wid >> 2;   // 0..1
  const int wc = wid & 3;    // 0..3
  const int l15 = lane & 15, lg = lane >> 4;
  const int bid = blockIdx.x;
  const int row0 = (bid & 15) << 8;
  const int col0 = (bid >> 4) << 8;
  const int NT = K >> 6;

  const int sr = t >> 3;
  const int su8 = (((t & 7) ^ (sr & 7)) << 3);  // pre-swizzled global elem offset
  const int t8 = t << 3;
  const u16* aG[4];
#pragma unroll
  for (int ga = 0; ga < 4; ++ga)
    aG[ga] = A + (size_t)(row0 + ga * 64 + sr) * K + su8;
  const u16* bG[4];
#pragma unroll
  for (int gb = 0; gb < 4; ++gb) {
    const int q = (gb * 2 + (sr >> 5)) & 3;
    const int nh = gb >> 1;
    bG[gb] = Bw + (size_t)(col0 + q * 64 + nh * 32 + (sr & 31)) * K + su8;
  }

  const int u0 = ((lg ^ (l15 & 7)) << 3);          // ks=0 unit
  const int u1 = (((4 | lg) ^ (l15 & 7)) << 3);    // ks=1 unit
  const int arow = (wr * 128 + l15) << 6;          // + m*1024
  const int brow = 16384 + ((wc * 32 + l15) << 6); // + nh*8192 + ni*1024

  f32x4 acc[8][4] = {};

#define STA(nb, ga, k0n)                                                              \
  __builtin_amdgcn_global_load_lds((const GLOBAL_AS void*)(aG[ga] + (k0n)),           \
                                   (LDS_AS void*)((nb) + (ga)*4096 + t8), 16, 0, 0)
#define STB(nb, gb, k0n)                                                              \
  __builtin_amdgcn_global_load_lds((const GLOBAL_AS void*)(bG[gb] + (k0n)),           \
                                   (LDS_AS void*)((nb) + 16384 + (gb)*4096 + t8), 16, 0, 0)

  {
    u16* nb = lds;
    STA(nb, 0, 0); STA(nb, 2, 0);
    STB(nb, 0, 0); STB(nb, 1, 0);
    STB(nb, 2, 0); STB(nb, 3, 0);
    STA(nb, 1, 0); STA(nb, 3, 0);
  }

  bf16x8 af[4][2], bl[2][2], bh[2][2];

  for (int kt = 0; kt < NT; ++kt) {
    const bool st = (kt + 1 < NT);
    const int k0n = (kt + 1) << 6;
    const u16* cb = lds + (kt & 1) * 32768;
    u16* nb = lds + ((kt + 1) & 1) * 32768;

    // ---- phase 0: mh=0, nh=0 ----
    asm volatile("s_waitcnt vmcnt(4)" ::: "memory");
    __builtin_amdgcn_s_barrier();
#pragma unroll
    for (int mi = 0; mi < 4; ++mi) {
      af[mi][0] = *(const bf16x8*)&cb[arow + mi * 1024 + u0];
      af[mi][1] = *(const bf16x8*)&cb[arow + mi * 1024 + u1];
    }
#pragma unroll
    for (int ni = 0; ni < 2; ++ni) {
      bl[ni][0] = *(const bf16x8*)&cb[brow + ni * 1024 + u0];
      bl[ni][1] = *(const bf16x8*)&cb[brow + ni * 1024 + u1];
    }
    if (st) { STA(nb, 0, k0n); STA(nb, 2, k0n); }
    __builtin_amdgcn_s_setprio(1);
#pragma unroll
    for (int mi = 0; mi < 4; ++mi)
#pragma unroll
      for (int ni = 0; ni < 2; ++ni) {
        acc[mi][ni] = __builtin_amdgcn_mfma_f32_16x16x32_bf16(af[mi][0], bl[ni][0], acc[mi][ni], 0, 0, 0);
        acc[mi][ni] = __builtin_amdgcn_mfma_f32_16x16x32_bf16(af[mi][1], bl[ni][1], acc[mi][ni], 0, 0, 0);
      }
    __builtin_amdgcn_s_setprio(0);

    // ---- phase 1: mh=0, nh=1 ----
    if (st) { asm volatile("s_waitcnt vmcnt(4)" ::: "memory"); }
    else    { asm volatile("s_waitcnt vmcnt(2)" ::: "memory"); }
    __builtin_amdgcn_s_barrier();
#pragma unroll
    for (int ni = 0; ni < 2; ++ni) {
      bh[ni][0] = *(const bf16x8*)&cb[brow + 8192 + ni * 1024 + u0];
      bh[ni][1] = *(const bf16x8*)&cb[brow + 8192 + ni * 1024 + u1];
    }
    if (st) { STB(nb, 0, k0n); STB(nb, 1, k0n); }
    __builtin_amdgcn_s_setprio(1);
#pragma unroll
    for (int mi = 0; mi < 4; ++mi)
#pragma unroll
      for (int ni = 0; ni < 2; ++ni) {
        acc[mi][2 + ni] = __builtin_amdgcn_mfma_f32_16x16x32_bf16(af[mi][0], bh[ni][0], acc[mi][2 + ni], 0, 0, 0);
        acc[mi][2 + ni] = __builtin_amdgcn_mfma_f32_16x16x32_bf16(af[mi][1], bh[ni][1], acc[mi][2 + ni], 0, 0, 0);
      }
    __builtin_amdgcn_s_setprio(0);

    // ---- phase 2: mh=1, nh=1 ----
    if (st) { asm volatile("s_waitcnt vmcnt(4)" ::: "memory"); }
    else    { asm volatile("s_waitcnt vmcnt(0)" ::: "memory"); }
    __builtin_amdgcn_s_barrier();
#pragma unroll
    for (int mi = 0; mi < 4; ++mi) {
      af[mi][0] = *(const bf16x8*)&cb[arow + (4 + mi) * 1024 + u0];
      af[mi][1] = *(const bf16x8*)&cb[arow + (4 + mi) * 1024 + u1];
    }
    if (st) { STB(nb, 2, k0n); STB(nb, 3, k0n); }
    __builtin_amdgcn_s_setprio(1);
#pragma unroll
    for (int mi = 0; mi < 4; ++mi)
#pragma unroll
      for (int ni = 0; ni < 2; ++ni) {
        acc[4 + mi][2 + ni] = __builtin_amdgcn_mfma_f32_16x16x32_bf16(af[mi][0], bh[ni][0], acc[4 + mi][2 + ni], 0, 0, 0);
        acc[4 + mi][2 + ni] = __builtin_amdgcn_mfma_f32_16x16x32_bf16(af[mi][1], bh[ni][1], acc[4 + mi][2 + ni], 0, 0, 0);
      }
    __builtin_amdgcn_s_setprio(0);

    // ---- phase 3: mh=1, nh=0 (no new reads) ----
    if (st) { STA(nb, 1, k0n); STA(nb, 3, k0n); }
    __builtin_amdgcn_s_setprio(1);
#pragma unroll
    for (int mi = 0; mi < 4; ++mi)
#pragma unroll
      for (int ni = 0; ni < 2; ++ni) {
        acc[4 + mi][ni] = __builtin_amdgcn_mfma_f32_16x16x32_bf16(af[mi][0], bl[ni][0], acc[4 + mi][ni], 0, 0, 0);
        acc[4 + mi][ni] = __builtin_amdgcn_mfma_f32_16x16x32_bf16(af[mi][1], bl[ni][1], acc[4 + mi][ni], 0, 0, 0);
      }
    __builtin_amdgcn_s_setprio(0);
  }
#undef STA
#undef STB

#pragma unroll
  for (int m = 0; m < 8; ++m) {
    const int row = row0 + wr * 128 + m * 16 + lg * 4;
#pragma unroll
    for (int n = 0; n < 4; ++n) {
      const int col = col0 + wc * 64 + n * 16 + l15;
#pragma unroll
      for (int r = 0; r < 4; ++r) {
        const size_t o = (size_t)(row + r) * N + col;
        if (OUTBF == 0) {
          C[o] = acc[m][n][r];
        } else if (OUTBF == 1) {
          C16[o] = f2bf(acc[m][n][r]);
        } else {
          const float g = bf2f(G[o]);
          C16[o] = f2bf(g / (1.0f + __expf(-g)) * acc[m][n][r]);
        }
      }
    }
  }
}

// ---------------- GEMM engine: 128x128, 8 waves (wave-tile 32x64), ring, epilogues ----------------
// Proven R8 ring schedule: 4-buf LDS ring, depth-3 prefetch, counted vmcnt 4/2/0.
// OUTBF: 0 f32 C = acc + R ; 3 rope-split (Q pre-scaled by 0.125*log2e for exp2 softmax).
template <int OUTBF>
__global__ __launch_bounds__(512, 2) void gemm128n(const u16* __restrict__ A,
                                                   const u16* __restrict__ Bw,
                                                   float* __restrict__ C,
                                                   const float* __restrict__ R,
                                                   const float* __restrict__ cosT,
                                                   const float* __restrict__ sinT,
                                                   u16* __restrict__ Qb,
                                                   u16* __restrict__ Kb,
                                                   u16* __restrict__ Vtb,
                                                   int N, int K) {
  __shared__ u16 lds[4 * 8192];  // 64 KB: 4 buffers x (A 128x32 | B 128x32)
  const int t = threadIdx.x;
  const int lane = t & 63;
  const int wid = t >> 6;
  const int wr = wid & 3;    // 0..3 : 32-row group
  const int wc = wid >> 2;   // 0..1 : 64-col group
  const int l15 = lane & 15, lg = lane >> 4;
  const int bid = blockIdx.x;
  const int row0 = (bid & 31) << 7;
  const int col0 = (bid >> 5) << 7;
  const int NT = K >> 5;

  const int rA = t >> 2;  // 0..127
  const int usw = (((t & 3) ^ ((t >> 3) & 3)) << 3);
  const u16* sA = A + (size_t)(row0 + rA) * K + usw;
  const u16* sB = Bw + (size_t)(col0 + rA) * K + usw;
  const int dst = t << 3;  // 0..4095

  const int e8 = ((lg ^ ((l15 >> 1) & 3)) << 3);
  const int aoff = (wr * 32 + l15) * 32 + e8;
  const int boff = 4096 + (wc * 64 + l15) * 32 + e8;

  f32x4 acc[2][4] = {};

  auto stage = [&](int kt) {
    u16* base = &lds[(kt & 3) * 8192];
    const size_t ko = (size_t)kt * 32;
    __builtin_amdgcn_global_load_lds((const GLOBAL_AS void*)(sA + ko),
                                     (LDS_AS void*)(base + dst), 16, 0, 0);
    __builtin_amdgcn_global_load_lds((const GLOBAL_AS void*)(sB + ko),
                                     (LDS_AS void*)(base + 4096 + dst), 16, 0, 0);
  };

  stage(0);
  stage(1);
  stage(2);

  for (int kt = 0; kt < NT; ++kt) {
    const int rem = NT - 1 - kt;
    if (rem >= 2) {
      asm volatile("s_waitcnt vmcnt(4)" ::: "memory");
    } else if (rem == 1) {
      asm volatile("s_waitcnt vmcnt(2)" ::: "memory");
    } else {
      asm volatile("s_waitcnt vmcnt(0)" ::: "memory");
    }
    __builtin_amdgcn_s_barrier();
    if (kt + 3 < NT) stage(kt + 3);
    const u16* base = &lds[(kt & 3) * 8192];
    bf16x8 af[2], bfv[4];
#pragma unroll
    for (int m = 0; m < 2; ++m) af[m] = *(const bf16x8*)&base[aoff + m * 512];
#pragma unroll
    for (int n = 0; n < 4; ++n) bfv[n] = *(const bf16x8*)&base[boff + n * 512];
    __builtin_amdgcn_s_setprio(1);
#pragma unroll
    for (int m = 0; m < 2; ++m)
#pragma unroll
      for (int n = 0; n < 4; ++n)
        acc[m][n] = __builtin_amdgcn_mfma_f32_16x16x32_bf16(af[m], bfv[n], acc[m][n], 0, 0, 0);
    __builtin_amdgcn_s_setprio(0);
  }

  if (OUTBF == 3) {
    // fused RoPE + QKV split. Tile entirely in Q (col0<1024), K, or V region.
    const int reg = col0 >> 10;
    const int fb = col0 & 1023;
#pragma unroll
    for (int m = 0; m < 2; ++m) {
      const int row = row0 + wr * 32 + m * 16 + lg * 4;
      const int b = row >> 11, tbase = row & 2047;
      if (reg < 2) {
        u16* dstp = (reg == 0) ? Qb : Kb;
        // Q pre-scaled by 0.125*log2(e) so attn softmax uses raw v_exp_f32 (2^x).
        const float qs = (reg == 0) ? 0.18033688011112042f : 1.0f;
#pragma unroll
        for (int n = 0; n < 2; ++n) {
          const int f = fb + wc * 64 + n * 16 + l15;
          const int h = f >> 6, j = f & 63;  // j < 32
#pragma unroll
          for (int r = 0; r < 4; ++r) {
            const int tt = tbase + r;
            const float c = cosT[tt * 32 + j], s = sinT[tt * 32 + j];
            const float x1 = acc[m][n][r], x2 = acc[m][n | 2][r];
            const size_t ro = ((size_t)(b * NHH + h) * TT + tt) * HDD + j;
            dstp[ro] = f2bf((x1 * c - x2 * s) * qs);
            dstp[ro + 32] = f2bf((x1 * s + x2 * c) * qs);
          }
        }
      } else {
#pragma unroll
        for (int n = 0; n < 4; ++n) {
          const int f = fb + wc * 64 + n * 16 + l15;
          const int h = f >> 6, j = f & 63;
          ushort4 pk;
          pk.x = f2bf(acc[m][n][0]);
          pk.y = f2bf(acc[m][n][1]);
          pk.z = f2bf(acc[m][n][2]);
          pk.w = f2bf(acc[m][n][3]);
          *(ushort4*)&Vtb[((size_t)(b * NHH + h) * HDD + j) * TT + tbase] = pk;
        }
      }
    }
    return;
  }

#pragma unroll
  for (int m = 0; m < 2; ++m) {
    const int row = row0 + wr * 32 + m * 16 + lg * 4;
#pragma unroll
    for (int n = 0; n < 4; ++n) {
      const int col = col0 + wc * 64 + n * 16 + l15;
#pragma unroll
      for (int r = 0; r < 4; ++r) {
        const size_t o = (size_t)(row + r) * N + col;
        C[o] = acc[m][n][r] + R[o];
      }
    }
  }
}

// ---------------- GEMM engine: dual-B 128x64 (g=A*W1^T, u=A*W2^T, silu fused), ----------------
// Ring: 3 bufs x 16KB, depth-2, counted vmcnt 2/0. A staged by all 8 waves,
// Bg by waves 0-3, Bu by waves 4-7 (2 glds/wave/stage -> uniform vmcnt math).
__global__ __launch_bounds__(512, 2) void gemm128d(const u16* __restrict__ A,
                                                   const u16* __restrict__ Bg,
                                                   const u16* __restrict__ Bu,
                                                   u16* __restrict__ C16,
                                                   int N, int K) {
  __shared__ u16 lds[3 * 8192];  // 48 KB: 3 bufs x (A 4096 | Bg 2048 | Bu 2048) u16
  const int t = threadIdx.x;
  const int lane = t & 63;
  const int wid = t >> 6;
  const int wr = wid & 3;    // 32-row group
  const int wc = wid >> 2;   // 0..1 : 32-col group
  const int l15 = lane & 15, lg = lane >> 4;
  const int bid = blockIdx.x;
  const int row0 = (bid & 31) << 7;   // 32 row tiles of 128
  const int col0 = (bid >> 5) << 6;   // 64-col tiles
  const int NT = K >> 5;

  const int rA = t >> 2;              // 0..127
  const int usw = (((t & 3) ^ ((t >> 3) & 3)) << 3);
  const u16* sA = A + (size_t)(row0 + rA) * K + usw;
  const int tb = t & 255;
  const int rB = tb >> 2;             // 0..63
  const int uswB = (((tb & 3) ^ ((tb >> 3) & 3)) << 3);
  const u16* sB = ((wid < 4) ? Bg : Bu) + (size_t)(col0 + rB) * K + uswB;
  const int dstA = t << 3;
  const int dstB = 4096 + ((wid < 4) ? 0 : 2048) + (tb << 3);

  const int e8 = ((lg ^ ((l15 >> 1) & 3)) << 3);
  const int aoff = (wr * 32 + l15) * 32 + e8;
  const int goff = 4096 + (wc * 32 + l15) * 32 + e8;
  const int uoff = 6144 + (wc * 32 + l15) * 32 + e8;

  f32x4 ag[2][2] = {}, au[2][2] = {};

  auto stage = [&](int kt, int buf) {
    u16* b = &lds[buf * 8192];
    const size_t ko = (size_t)kt * 32;
    __builtin_amdgcn_global_load_lds((const GLOBAL_AS void*)(sA + ko),
                                     (LDS_AS void*)(b + dstA), 16, 0, 0);
    __builtin_amdgcn_global_load_lds((const GLOBAL_AS void*)(sB + ko),
                                     (LDS_AS void*)(b + dstB), 16, 0, 0);
  };

  stage(0, 0);
  stage(1, 1);

  int cbuf = 0;
  for (int kt = 0; kt < NT; ++kt) {
    if (kt + 1 < NT) {
      asm volatile("s_waitcnt vmcnt(2)" ::: "memory");
    } else {
      asm volatile("s_waitcnt vmcnt(0)" ::: "memory");
    }
    __builtin_amdgcn_s_barrier();
    const int nbuf = (cbuf == 2) ? 0 : cbuf + 1;
    const int sbuf = (nbuf == 2) ? 0 : nbuf + 1;
    if (kt + 2 < NT) stage(kt + 2, sbuf);
    const u16* cb = &lds[cbuf * 8192];
    bf16x8 af[2], bgv[2], buv[2];
#pragma unroll
    for (int m = 0; m < 2; ++m) af[m] = *(const bf16x8*)&cb[aoff + m * 512];
#pragma unroll
    for (int n = 0; n < 2; ++n) {
      bgv[n] = *(const bf16x8*)&cb[goff + n * 512];
      buv[n] = *(const bf16x8*)&cb[uoff + n * 512];
    }
    __builtin_amdgcn_s_setprio(1);
#pragma unroll
    for (int m = 0; m < 2; ++m)
#pragma unroll
      for (int n = 0; n < 2; ++n) {
        ag[m][n] = __builtin_amdgcn_mfma_f32_16x16x32_bf16(af[m], bgv[n], ag[m][n], 0, 0, 0);
        au[m][n] = __builtin_amdgcn_mfma_f32_16x16x32_bf16(af[m], buv[n], au[m][n], 0, 0, 0);
      }
    __builtin_amdgcn_s_setprio(0);
    cbuf = nbuf;
  }

#pragma unroll
  for (int m = 0; m < 2; ++m) {
    const int row = row0 + wr * 32 + m * 16 + lg * 4;
#pragma unroll
    for (int n = 0; n < 2; ++n) {
      const int col = col0 + wc * 32 + n * 16 + l15;
#pragma unroll
      for (int r = 0; r < 4; ++r) {
        const float g = ag[m][n][r];
        const float u = au[m][n][r];
        C16[(size_t)(row + r) * N + col] = f2bf(g / (1.0f + __expf(-g)) * u);
      }
    }
  }
}

// ---------------- attention: flash-style, no-max exp2 softmax (Q pre-scaled), ----------------
// denominator via MFMA row-sum; P->bf16 via v_cvt_pk; causal load-balanced grid.
__global__ __launch_bounds__(256) void attn_k(const u16* __restrict__ Q,
                                              const u16* __restrict__ Kc,
                                              const u16* __restrict__ Vt,
                                              u16* __restrict__ O) {
  __shared__ u16 P_lds[4][32][72];
  const int bid = blockIdx.x;           // 512 blocks
  const int bh = bid & 31;
  const int jj = bid >> 5;              // 0..15
  const int qi = (bid < 256) ? jj : 23 - jj;
  const int q0 = qi << 7;
  const int lane = threadIdx.x & 63;
  const int w = threadIdx.x >> 6;
  const int l15 = lane & 15, lg = lane >> 4;
  const int qbase = q0 + w * 32;

  bf16x8 qf[2][2];
#pragma unroll
  for (int am = 0; am < 2; ++am)
#pragma unroll
    for (int ks = 0; ks < 2; ++ks)
      qf[am][ks] = *(const bf16x8*)&Q[((size_t)bh * TT + qbase + am * 16 + l15) * HDD + ks * 32 + lg * 8];

  bf16x8 ones;
#pragma unroll
  for (int i = 0; i < 8; ++i) ones[i] = (short)0x3F80;  // bf16 1.0

  f32x4 oacc[2][4] = {};
  f32x4 lacc[2] = {};

  const int ntile = (q0 + 128) >> 6;
  for (int kt = 0; kt < ntile; ++kt) {
    const int k0 = kt << 6;
    f32x4 s[2][4];
    bf16x8 kf0[4], kf1[4];
#pragma unroll
    for (int an = 0; an < 4; ++an) {
      kf0[an] = *(const bf16x8*)&Kc[((size_t)bh * TT + k0 + an * 16 + l15) * HDD + lg * 8];
      kf1[an] = *(const bf16x8*)&Kc[((size_t)bh * TT + k0 + an * 16 + l15) * HDD + 32 + lg * 8];
    }
    __builtin_amdgcn_s_setprio(1);
#pragma unroll
    for (int an = 0; an < 4; ++an) {
#pragma unroll
      for (int am = 0; am < 2; ++am) {
        f32x4 z = {0.0f, 0.0f, 0.0f, 0.0f};
        z = __builtin_amdgcn_mfma_f32_16x16x32_bf16(qf[am][0], kf0[an], z, 0, 0, 0);
        s[am][an] = __builtin_amdgcn_mfma_f32_16x16x32_bf16(qf[am][1], kf1[an], z, 0, 0, 0);
      }
    }
    __builtin_amdgcn_s_setprio(0);
    // causal mask + 2^x (Q pre-scaled by 0.125*log2e; scores bounded, f32-safe)
    const bool diag = (k0 + 64) > q0;
#pragma unroll
    for (int am = 0; am < 2; ++am)
#pragma unroll
      for (int an = 0; an < 4; ++an)
#pragma unroll
        for (int r = 0; r < 4; ++r) {
          float v = s[am][an][r];
          if (diag) {
            const int qrow = qbase + am * 16 + lg * 4 + r;
            const int kcol = k0 + an * 16 + l15;
            if (kcol > qrow) v = -1e30f;
          }
          float p;
          asm("v_exp_f32 %0, %1" : "=v"(p) : "v"(v));
          s[am][an][r] = p;
        }
    // P -> LDS via packed bf16 conversion, then PV + l-sum MFMA
#pragma unroll
    for (int am = 0; am < 2; ++am)
#pragma unroll
      for (int an = 0; an < 4; ++an)
#pragma unroll
        for (int rp = 0; rp < 2; ++rp) {
          u32 pk;
          asm("v_cvt_pk_bf16_f32 %0, %1, %2"
              : "=v"(pk) : "v"(s[am][an][2 * rp]), "v"(s[am][an][2 * rp + 1]));
          const int rowb = am * 16 + lg * 4 + 2 * rp;
          P_lds[w][rowb][an * 16 + l15] = (u16)pk;
          P_lds[w][rowb + 1][an * 16 + l15] = (u16)(pk >> 16);
        }
#pragma unroll
    for (int ks = 0; ks < 2; ++ks) {
      bf16x8 pf[2];
#pragma unroll
      for (int am = 0; am < 2; ++am)
        pf[am] = *(const bf16x8*)&P_lds[w][am * 16 + l15][ks * 32 + lg * 8];
      __builtin_amdgcn_s_setprio(1);
#pragma unroll
      for (int dn = 0; dn < 4; ++dn) {
        const bf16x8 vf = *(const bf16x8*)&Vt[((size_t)bh * HDD + dn * 16 + l15) * TT + k0 + ks * 32 + lg * 8];
#pragma unroll
        for (int am = 0; am < 2; ++am)
          oacc[am][dn] = __builtin_amdgcn_mfma_f32_16x16x32_bf16(pf[am], vf, oacc[am][dn], 0, 0, 0);
      }
#pragma unroll
      for (int am = 0; am < 2; ++am)
        lacc[am] = __builtin_amdgcn_mfma_f32_16x16x32_bf16(pf[am], ones, lacc[am], 0, 0, 0);
      __builtin_amdgcn_s_setprio(0);
    }
  }
  const int b = bh >> 4, h = bh & 15;
#pragma unroll
  for (int am = 0; am < 2; ++am)
#pragma unroll
    for (int r = 0; r < 4; ++r) {
      const float il = 1.0f / lacc[am][r];
      const int qrow = qbase + am * 16 + lg * 4 + r;
#pragma unroll
      for (int dn = 0; dn < 4; ++dn)
        O[((size_t)b * TT + qrow) * EE + h * 64 + dn * 16 + l15] = f2bf(oacc[am][dn][r] * il);
    }
}

// ---------------- host ----------------

extern "C" void kernel_launch(void* const* d_in, const int* in_sizes, int n_in,
                              void* d_out, int out_size, void* d_ws, size_t ws_size,
                              hipStream_t stream) {
  const int* idx = (const int*)d_in[0];
  const float* tok_emb = (const float*)d_in[1];
  const float* qkv_w = (const float*)d_in[2];
  const float* proj_w = (const float*)d_in[3];
  const float* w1 = (const float*)d_in[4];
  const float* w2 = (const float*)d_in[5];
  const float* w3 = (const float*)d_in[6];
  const float* norm1_w = (const float*)d_in[7];
  const float* norm2_w = (const float*)d_in[8];
  const float* norm_f_w = (const float*)d_in[9];
  float* out = (float*)d_out;

  char* ws = (char*)d_ws;
  size_t off = 0;
  auto alloc = [&](size_t bytes) -> void* {
    off = (off + 255) & ~(size_t)255;
    void* p = ws + off;
    off += bytes;
    return p;
  };

  const size_t N_TEMB = (size_t)VV * EE;
  const size_t N_QKVW = (size_t)8 * 3 * EE * EE;
  const size_t N_PROJW = (size_t)8 * EE * EE;
  const size_t N_W1 = (size_t)8 * HIDD * EE;
  const size_t N_W3 = (size_t)8 * EE * HIDD;

  u16* tembbf = (u16*)alloc(N_TEMB * 2);
  u16* qkvwbf = (u16*)alloc(N_QKVW * 2);
  u16* projwbf = (u16*)alloc(N_PROJW * 2);
  u16* w1bf = (u16*)alloc(N_W1 * 2);
  u16* w2bf = (u16*)alloc(N_W1 * 2);
  u16* w3bf = (u16*)alloc(N_W3 * 2);
  float* x = (float*)alloc((size_t)MM * EE * 4);
  u16* h1 = (u16*)alloc((size_t)MM * EE * 2);
  u16* hg = (u16*)alloc((size_t)MM * HIDD * 2);
  u16* qb = (u16*)alloc((size_t)2 * NHH * TT * HDD * 2);
  u16* kb = (u16*)alloc((size_t)2 * NHH * TT * HDD * 2);
  u16* vtb = (u16*)alloc((size_t)2 * NHH * TT * HDD * 2);
  u16* attno = (u16*)alloc((size_t)MM * EE * 2);
  float* cosT = (float*)alloc((size_t)TT * 32 * 4);
  float* sinT = (float*)alloc((size_t)TT * 32 * 4);

  auto cast = [&](const float* src, u16* dst, size_t n) {
    const long n4 = (long)(n / 4);
    castbf_k<<<(int)((n4 + 255) / 256), 256, 0, stream>>>(src, dst, n4);
  };
  cast(tok_emb, tembbf, N_TEMB);
  cast(qkv_w, qkvwbf, N_QKVW);
  cast(proj_w, projwbf, N_PROJW);
  cast(w1, w1bf, N_W1);
  cast(w2, w2bf, N_W1);
  cast(w3, w3bf, N_W3);

  ropetab_k<<<TT, 32, 0, stream>>>(cosT, sinT);
  embed_k<<<MM, 256, 0, stream>>>(idx, tok_emb, x);

  for (int l = 0; l < 8; ++l) {
    rmsnorm_k<<<MM, 256, 0, stream>>>(x, norm1_w + l * EE, h1);
    gemm128n<3><<<dim3(24 * 32), 512, 0, stream>>>(h1, qkvwbf + (size_t)l * 3 * EE * EE,
                                                   nullptr, nullptr,
                                                   cosT, sinT, qb, kb, vtb, 3 * EE, EE);
    attn_k<<<dim3(512), 256, 0, stream>>>(qb, kb, vtb, attno);
    gemm128n<0><<<dim3(8 * 32), 512, 0, stream>>>(attno, projwbf + (size_t)l * EE * EE,
                                                  x, x,
                                                  nullptr, nullptr, nullptr, nullptr, nullptr,
                                                  EE, EE);
    rmsnorm_k<<<MM, 256, 0, stream>>>(x, norm2_w + l * EE, h1);
    gemm128d<<<dim3(44 * 32), 512, 0, stream>>>(h1, w1bf + (size_t)l * HIDD * EE,
                                                w2bf + (size_t)l * HIDD * EE,
                                                hg, HIDD, EE);
    gemm128n<0><<<dim3(8 * 32), 512, 0, stream>>>(hg, w3bf + (size_t)l * EE * HIDD,
                                                  x, x,
                                                  nullptr, nullptr, nullptr, nullptr, nullptr,
                                                  EE, HIDD);
  }
  rmsnorm_k<<<MM, 256, 0, stream>>>(x, norm_f_w, h1);
  gemm256p<0><<<dim3(125 * 16), 512, 0, stream>>>(h1, tembbf, out, nullptr, nullptr,
                                                  VV, EE);
}

// Round 15
// 2423.051 us; speedup vs baseline: 1.1505x; 1.0000x over previous
//
#include <hip/hip_runtime.h>

#define GLOBAL_AS __attribute__((address_space(1)))
#define LDS_AS __attribute__((address_space(3)))

typedef unsigned short u16;
typedef unsigned int u32;
typedef __attribute__((ext_vector_type(4))) float f32x4;
typedef __attribute__((ext_vector_type(8))) short bf16x8;

// Model dims
#define TT 2048
#define EE 1024
#define NHH 16
#define HDD 64
#define HIDD 2816
#define VV 32000
#define MM 4096   // B*T

__device__ __forceinline__ u16 f2bf(float f) {
  u32 u = __builtin_bit_cast(u32, f);
  u += 0x7fffu + ((u >> 16) & 1u);
  return (u16)(u >> 16);
}
__device__ __forceinline__ float bf2f(u16 v) {
  return __builtin_bit_cast(float, (u32)v << 16);
}

// ---------------- elementwise / staging kernels ----------------

__global__ __launch_bounds__(256) void castbf_k(const float* __restrict__ in,
                                                u16* __restrict__ o, long n4) {
  const long i = (long)blockIdx.x * 256 + threadIdx.x;
  if (i >= n4) return;
  const float4 v = ((const float4*)in)[i];
  ((uint2*)o)[i] = make_uint2((u32)f2bf(v.x) | ((u32)f2bf(v.y) << 16),
                              (u32)f2bf(v.z) | ((u32)f2bf(v.w) << 16));
}

__global__ void ropetab_k(float* __restrict__ cosT, float* __restrict__ sinT) {
  const int t = blockIdx.x, j = threadIdx.x;  // j in [0,32)
  const float inv = powf(10000.0f, -(float)j * (1.0f / 32.0f));
  const float f = (float)t * inv;
  cosT[t * 32 + j] = cosf(f);
  sinT[t * 32 + j] = sinf(f);
}

__global__ __launch_bounds__(256) void embed_k(const int* __restrict__ idx,
                                               const float* __restrict__ temb,
                                               float* __restrict__ x) {
  const int row = blockIdx.x;
  const int id = idx[row];
  ((float4*)(x + (size_t)row * EE))[threadIdx.x] =
      ((const float4*)(temb + (size_t)id * EE))[threadIdx.x];
}

__global__ __launch_bounds__(256) void rmsnorm_k(const float* __restrict__ x,
                                                 const float* __restrict__ w,
                                                 u16* __restrict__ o) {
  __shared__ float red[4];
  const int row = blockIdx.x, tid = threadIdx.x;
  const float4 v = ((const float4*)(x + (size_t)row * EE))[tid];
  float ss = v.x * v.x + v.y * v.y + v.z * v.z + v.w * v.w;
#pragma unroll
  for (int off = 32; off; off >>= 1) ss += __shfl_xor(ss, off, 64);
  if ((tid & 63) == 0) red[tid >> 6] = ss;
  __syncthreads();
  const float inv = rsqrtf((red[0] + red[1] + red[2] + red[3]) * (1.0f / 1024.0f) + 1e-6f);
  const float4 wv = ((const float4*)w)[tid];
  const u32 lo = (u32)f2bf(v.x * inv * wv.x) | ((u32)f2bf(v.y * inv * wv.y) << 16);
  const u32 hi = (u32)f2bf(v.z * inv * wv.z) | ((u32)f2bf(v.w * inv * wv.w) << 16);
  ((uint2*)(o + (size_t)row * EE))[tid] = make_uint2(lo, hi);
}

// ---------------- GEMM engine: 256x256, BK=64, 4-phase counted-vmcnt dbuf (R5 engine) ----------------
// Used for the logits GEMM only (grid 2000 blocks). Best measured schedule (38% MfmaUtil).
// OUTBF==0 uses nontemporal C stores: C is the final output (never re-read); bypassing
// L2/L3 keeps the temb B-panels resident (FETCH 288 MB -> ~ideal 75 MB).
template <int OUTBF>
__global__ __launch_bounds__(512, 2) void gemm256p(const u16* __restrict__ A,
                                                   const u16* __restrict__ Bw,
                                                   float* __restrict__ C,
                                                   u16* __restrict__ C16,
                                                   const u16* __restrict__ G,
                                                   int N, int K) {
  __shared__ u16 lds[2 * 32768];  // 128 KB
  const int t = threadIdx.x;
  const int lane = t & 63;
  const int wid = t >> 6;
  const int wr = wid >> 2;   // 0..1
  const int wc = wid & 3;    // 0..3
  const int l15 = lane & 15, lg = lane >> 4;
  const int bid = blockIdx.x;
  const int row0 = (bid & 15) << 8;
  const int col0 = (bid >> 4) << 8;
  const int NT = K >> 6;

  const int sr = t >> 3;
  const int su8 = (((t & 7) ^ (sr & 7)) << 3);  // pre-swizzled global elem offset
  const int t8 = t << 3;
  const u16* aG[4];
#pragma unroll
  for (int ga = 0; ga < 4; ++ga)
    aG[ga] = A + (size_t)(row0 + ga * 64 + sr) * K + su8;
  const u16* bG[4];
#pragma unroll
  for (int gb = 0; gb < 4; ++gb) {
    const int q = (gb * 2 + (sr >> 5)) & 3;
    const int nh = gb >> 1;
    bG[gb] = Bw + (size_t)(col0 + q * 64 + nh * 32 + (sr & 31)) * K + su8;
  }

  const int u0 = ((lg ^ (l15 & 7)) << 3);          // ks=0 unit
  const int u1 = (((4 | lg) ^ (l15 & 7)) << 3);    // ks=1 unit
  const int arow = (wr * 128 + l15) << 6;          // + m*1024
  const int brow = 16384 + ((wc * 32 + l15) << 6); // + nh*8192 + ni*1024

  f32x4 acc[8][4] = {};

#define STA(nb, ga, k0n)                                                              \
  __builtin_amdgcn_global_load_lds((const GLOBAL_AS void*)(aG[ga] + (k0n)),           \
                                   (LDS_AS void*)((nb) + (ga)*4096 + t8), 16, 0, 0)
#define STB(nb, gb, k0n)                                                              \
  __builtin_amdgcn_global_load_lds((const GLOBAL_AS void*)(bG[gb] + (k0n)),           \
                                   (LDS_AS void*)((nb) + 16384 + (gb)*4096 + t8), 16, 0, 0)

  {
    u16* nb = lds;
    STA(nb, 0, 0); STA(nb, 2, 0);
    STB(nb, 0, 0); STB(nb, 1, 0);
    STB(nb, 2, 0); STB(nb, 3, 0);
    STA(nb, 1, 0); STA(nb, 3, 0);
  }

  bf16x8 af[4][2], bl[2][2], bh[2][2];

  for (int kt = 0; kt < NT; ++kt) {
    const bool st = (kt + 1 < NT);
    const int k0n = (kt + 1) << 6;
    const u16* cb = lds + (kt & 1) * 32768;
    u16* nb = lds + ((kt + 1) & 1) * 32768;

    // ---- phase 0: mh=0, nh=0 ----
    asm volatile("s_waitcnt vmcnt(4)" ::: "memory");
    __builtin_amdgcn_s_barrier();
#pragma unroll
    for (int mi = 0; mi < 4; ++mi) {
      af[mi][0] = *(const bf16x8*)&cb[arow + mi * 1024 + u0];
      af[mi][1] = *(const bf16x8*)&cb[arow + mi * 1024 + u1];
    }
#pragma unroll
    for (int ni = 0; ni < 2; ++ni) {
      bl[ni][0] = *(const bf16x8*)&cb[brow + ni * 1024 + u0];
      bl[ni][1] = *(const bf16x8*)&cb[brow + ni * 1024 + u1];
    }
    if (st) { STA(nb, 0, k0n); STA(nb, 2, k0n); }
    __builtin_amdgcn_s_setprio(1);
#pragma unroll
    for (int mi = 0; mi < 4; ++mi)
#pragma unroll
      for (int ni = 0; ni < 2; ++ni) {
        acc[mi][ni] = __builtin_amdgcn_mfma_f32_16x16x32_bf16(af[mi][0], bl[ni][0], acc[mi][ni], 0, 0, 0);
        acc[mi][ni] = __builtin_amdgcn_mfma_f32_16x16x32_bf16(af[mi][1], bl[ni][1], acc[mi][ni], 0, 0, 0);
      }
    __builtin_amdgcn_s_setprio(0);

    // ---- phase 1: mh=0, nh=1 ----
    if (st) { asm volatile("s_waitcnt vmcnt(4)" ::: "memory"); }
    else    { asm volatile("s_waitcnt vmcnt(2)" ::: "memory"); }
    __builtin_amdgcn_s_barrier();
#pragma unroll
    for (int ni = 0; ni < 2; ++ni) {
      bh[ni][0] = *(const bf16x8*)&cb[brow + 8192 + ni * 1024 + u0];
      bh[ni][1] = *(const bf16x8*)&cb[brow + 8192 + ni * 1024 + u1];
    }
    if (st) { STB(nb, 0, k0n); STB(nb, 1, k0n); }
    __builtin_amdgcn_s_setprio(1);
#pragma unroll
    for (int mi = 0; mi < 4; ++mi)
#pragma unroll
      for (int ni = 0; ni < 2; ++ni) {
        acc[mi][2 + ni] = __builtin_amdgcn_mfma_f32_16x16x32_bf16(af[mi][0], bh[ni][0], acc[mi][2 + ni], 0, 0, 0);
        acc[mi][2 + ni] = __builtin_amdgcn_mfma_f32_16x16x32_bf16(af[mi][1], bh[ni][1], acc[mi][2 + ni], 0, 0, 0);
      }
    __builtin_amdgcn_s_setprio(0);

    // ---- phase 2: mh=1, nh=1 ----
    if (st) { asm volatile("s_waitcnt vmcnt(4)" ::: "memory"); }
    else    { asm volatile("s_waitcnt vmcnt(0)" ::: "memory"); }
    __builtin_amdgcn_s_barrier();
#pragma unroll
    for (int mi = 0; mi < 4; ++mi) {
      af[mi][0] = *(const bf16x8*)&cb[arow + (4 + mi) * 1024 + u0];
      af[mi][1] = *(const bf16x8*)&cb[arow + (4 + mi) * 1024 + u1];
    }
    if (st) { STB(nb, 2, k0n); STB(nb, 3, k0n); }
    __builtin_amdgcn_s_setprio(1);
#pragma unroll
    for (int mi = 0; mi < 4; ++mi)
#pragma unroll
      for (int ni = 0; ni < 2; ++ni) {
        acc[4 + mi][2 + ni] = __builtin_amdgcn_mfma_f32_16x16x32_bf16(af[mi][0], bh[ni][0], acc[4 + mi][2 + ni], 0, 0, 0);
        acc[4 + mi][2 + ni] = __builtin_amdgcn_mfma_f32_16x16x32_bf16(af[mi][1], bh[ni][1], acc[4 + mi][2 + ni], 0, 0, 0);
      }
    __builtin_amdgcn_s_setprio(0);

    // ---- phase 3: mh=1, nh=0 (no new reads) ----
    if (st) { STA(nb, 1, k0n); STA(nb, 3, k0n); }
    __builtin_amdgcn_s_setprio(1);
#pragma unroll
    for (int mi = 0; mi < 4; ++mi)
#pragma unroll
      for (int ni = 0; ni < 2; ++ni) {
        acc[4 + mi][ni] = __builtin_amdgcn_mfma_f32_16x16x32_bf16(af[mi][0], bl[ni][0], acc[4 + mi][ni], 0, 0, 0);
        acc[4 + mi][ni] = __builtin_amdgcn_mfma_f32_16x16x32_bf16(af[mi][1], bl[ni][1], acc[4 + mi][ni], 0, 0, 0);
      }
    __builtin_amdgcn_s_setprio(0);
  }
#undef STA
#undef STB

#pragma unroll
  for (int m = 0; m < 8; ++m) {
    const int row = row0 + wr * 128 + m * 16 + lg * 4;
#pragma unroll
    for (int n = 0; n < 4; ++n) {
      const int col = col0 + wc * 64 + n * 16 + l15;
#pragma unroll
      for (int r = 0; r < 4; ++r) {
        const size_t o = (size_t)(row + r) * N + col;
        if (OUTBF == 0) {
          __builtin_nontemporal_store(acc[m][n][r], &C[o]);
        } else if (OUTBF == 1) {
          C16[o] = f2bf(acc[m][n][r]);
        } else {
          const float g = bf2f(G[o]);
          C16[o] = f2bf(g / (1.0f + __expf(-g)) * acc[m][n][r]);
        }
      }
    }
  }
}

// ---------------- GEMM engine: 128x128, 8 waves (wave-tile 32x64), ring, epilogues ----------------
// Proven R8 ring schedule: 4-buf LDS ring, depth-3 prefetch, counted vmcnt 4/2/0.
// OUTBF: 0 f32 C = acc + R ; 3 rope-split (Q pre-scaled by 0.125*log2e for exp2 softmax).
template <int OUTBF>
__global__ __launch_bounds__(512, 2) void gemm128n(const u16* __restrict__ A,
                                                   const u16* __restrict__ Bw,
                                                   float* __restrict__ C,
                                                   const float* __restrict__ R,
                                                   const float* __restrict__ cosT,
                                                   const float* __restrict__ sinT,
                                                   u16* __restrict__ Qb,
                                                   u16* __restrict__ Kb,
                                                   u16* __restrict__ Vtb,
                                                   int N, int K) {
  __shared__ u16 lds[4 * 8192];  // 64 KB: 4 buffers x (A 128x32 | B 128x32)
  const int t = threadIdx.x;
  const int lane = t & 63;
  const int wid = t >> 6;
  const int wr = wid & 3;    // 0..3 : 32-row group
  const int wc = wid >> 2;   // 0..1 : 64-col group
  const int l15 = lane & 15, lg = lane >> 4;
  const int bid = blockIdx.x;
  const int row0 = (bid & 31) << 7;
  const int col0 = (bid >> 5) << 7;
  const int NT = K >> 5;

  const int rA = t >> 2;  // 0..127
  const int usw = (((t & 3) ^ ((t >> 3) & 3)) << 3);
  const u16* sA = A + (size_t)(row0 + rA) * K + usw;
  const u16* sB = Bw + (size_t)(col0 + rA) * K + usw;
  const int dst = t << 3;  // 0..4095

  const int e8 = ((lg ^ ((l15 >> 1) & 3)) << 3);
  const int aoff = (wr * 32 + l15) * 32 + e8;
  const int boff = 4096 + (wc * 64 + l15) * 32 + e8;

  f32x4 acc[2][4] = {};

  auto stage = [&](int kt) {
    u16* base = &lds[(kt & 3) * 8192];
    const size_t ko = (size_t)kt * 32;
    __builtin_amdgcn_global_load_lds((const GLOBAL_AS void*)(sA + ko),
                                     (LDS_AS void*)(base + dst), 16, 0, 0);
    __builtin_amdgcn_global_load_lds((const GLOBAL_AS void*)(sB + ko),
                                     (LDS_AS void*)(base + 4096 + dst), 16, 0, 0);
  };

  stage(0);
  stage(1);
  stage(2);

  for (int kt = 0; kt < NT; ++kt) {
    const int rem = NT - 1 - kt;
    if (rem >= 2) {
      asm volatile("s_waitcnt vmcnt(4)" ::: "memory");
    } else if (rem == 1) {
      asm volatile("s_waitcnt vmcnt(2)" ::: "memory");
    } else {
      asm volatile("s_waitcnt vmcnt(0)" ::: "memory");
    }
    __builtin_amdgcn_s_barrier();
    if (kt + 3 < NT) stage(kt + 3);
    const u16* base = &lds[(kt & 3) * 8192];
    bf16x8 af[2], bfv[4];
#pragma unroll
    for (int m = 0; m < 2; ++m) af[m] = *(const bf16x8*)&base[aoff + m * 512];
#pragma unroll
    for (int n = 0; n < 4; ++n) bfv[n] = *(const bf16x8*)&base[boff + n * 512];
    __builtin_amdgcn_s_setprio(1);
#pragma unroll
    for (int m = 0; m < 2; ++m)
#pragma unroll
      for (int n = 0; n < 4; ++n)
        acc[m][n] = __builtin_amdgcn_mfma_f32_16x16x32_bf16(af[m], bfv[n], acc[m][n], 0, 0, 0);
    __builtin_amdgcn_s_setprio(0);
  }

  if (OUTBF == 3) {
    // fused RoPE + QKV split. Tile entirely in Q (col0<1024), K, or V region.
    const int reg = col0 >> 10;
    const int fb = col0 & 1023;
#pragma unroll
    for (int m = 0; m < 2; ++m) {
      const int row = row0 + wr * 32 + m * 16 + lg * 4;
      const int b = row >> 11, tbase = row & 2047;
      if (reg < 2) {
        u16* dstp = (reg == 0) ? Qb : Kb;
        // Q pre-scaled by 0.125*log2(e) so attn softmax uses raw v_exp_f32 (2^x).
        const float qs = (reg == 0) ? 0.18033688011112042f : 1.0f;
#pragma unroll
        for (int n = 0; n < 2; ++n) {
          const int f = fb + wc * 64 + n * 16 + l15;
          const int h = f >> 6, j = f & 63;  // j < 32
#pragma unroll
          for (int r = 0; r < 4; ++r) {
            const int tt = tbase + r;
            const float c = cosT[tt * 32 + j], s = sinT[tt * 32 + j];
            const float x1 = acc[m][n][r], x2 = acc[m][n | 2][r];
            const size_t ro = ((size_t)(b * NHH + h) * TT + tt) * HDD + j;
            dstp[ro] = f2bf((x1 * c - x2 * s) * qs);
            dstp[ro + 32] = f2bf((x1 * s + x2 * c) * qs);
          }
        }
      } else {
#pragma unroll
        for (int n = 0; n < 4; ++n) {
          const int f = fb + wc * 64 + n * 16 + l15;
          const int h = f >> 6, j = f & 63;
          ushort4 pk;
          pk.x = f2bf(acc[m][n][0]);
          pk.y = f2bf(acc[m][n][1]);
          pk.z = f2bf(acc[m][n][2]);
          pk.w = f2bf(acc[m][n][3]);
          *(ushort4*)&Vtb[((size_t)(b * NHH + h) * HDD + j) * TT + tbase] = pk;
        }
      }
    }
    return;
  }

#pragma unroll
  for (int m = 0; m < 2; ++m) {
    const int row = row0 + wr * 32 + m * 16 + lg * 4;
#pragma unroll
    for (int n = 0; n < 4; ++n) {
      const int col = col0 + wc * 64 + n * 16 + l15;
#pragma unroll
      for (int r = 0; r < 4; ++r) {
        const size_t o = (size_t)(row + r) * N + col;
        C[o] = acc[m][n][r] + R[o];
      }
    }
  }
}

// ---------------- GEMM engine: dual-B 128x64 (g=A*W1^T, u=A*W2^T, silu fused), ----------------
// Ring: 3 bufs x 16KB, depth-2, counted vmcnt 2/0. A staged by all 8 waves,
// Bg by waves 0-3, Bu by waves 4-7 (2 glds/wave/stage -> uniform vmcnt math).
__global__ __launch_bounds__(512, 2) void gemm128d(const u16* __restrict__ A,
                                                   const u16* __restrict__ Bg,
                                                   const u16* __restrict__ Bu,
                                                   u16* __restrict__ C16,
                                                   int N, int K) {
  __shared__ u16 lds[3 * 8192];  // 48 KB: 3 bufs x (A 4096 | Bg 2048 | Bu 2048) u16
  const int t = threadIdx.x;
  const int lane = t & 63;
  const int wid = t >> 6;
  const int wr = wid & 3;    // 32-row group
  const int wc = wid >> 2;   // 0..1 : 32-col group
  const int l15 = lane & 15, lg = lane >> 4;
  const int bid = blockIdx.x;
  const int row0 = (bid & 31) << 7;   // 32 row tiles of 128
  const int col0 = (bid >> 5) << 6;   // 64-col tiles
  const int NT = K >> 5;

  const int rA = t >> 2;              // 0..127
  const int usw = (((t & 3) ^ ((t >> 3) & 3)) << 3);
  const u16* sA = A + (size_t)(row0 + rA) * K + usw;
  const int tb = t & 255;
  const int rB = tb >> 2;             // 0..63
  const int uswB = (((tb & 3) ^ ((tb >> 3) & 3)) << 3);
  const u16* sB = ((wid < 4) ? Bg : Bu) + (size_t)(col0 + rB) * K + uswB;
  const int dstA = t << 3;
  const int dstB = 4096 + ((wid < 4) ? 0 : 2048) + (tb << 3);

  const int e8 = ((lg ^ ((l15 >> 1) & 3)) << 3);
  const int aoff = (wr * 32 + l15) * 32 + e8;
  const int goff = 4096 + (wc * 32 + l15) * 32 + e8;
  const int uoff = 6144 + (wc * 32 + l15) * 32 + e8;

  f32x4 ag[2][2] = {}, au[2][2] = {};

  auto stage = [&](int kt, int buf) {
    u16* b = &lds[buf * 8192];
    const size_t ko = (size_t)kt * 32;
    __builtin_amdgcn_global_load_lds((const GLOBAL_AS void*)(sA + ko),
                                     (LDS_AS void*)(b + dstA), 16, 0, 0);
    __builtin_amdgcn_global_load_lds((const GLOBAL_AS void*)(sB + ko),
                                     (LDS_AS void*)(b + dstB), 16, 0, 0);
  };

  stage(0, 0);
  stage(1, 1);

  int cbuf = 0;
  for (int kt = 0; kt < NT; ++kt) {
    if (kt + 1 < NT) {
      asm volatile("s_waitcnt vmcnt(2)" ::: "memory");
    } else {
      asm volatile("s_waitcnt vmcnt(0)" ::: "memory");
    }
    __builtin_amdgcn_s_barrier();
    const int nbuf = (cbuf == 2) ? 0 : cbuf + 1;
    const int sbuf = (nbuf == 2) ? 0 : nbuf + 1;
    if (kt + 2 < NT) stage(kt + 2, sbuf);
    const u16* cb = &lds[cbuf * 8192];
    bf16x8 af[2], bgv[2], buv[2];
#pragma unroll
    for (int m = 0; m < 2; ++m) af[m] = *(const bf16x8*)&cb[aoff + m * 512];
#pragma unroll
    for (int n = 0; n < 2; ++n) {
      bgv[n] = *(const bf16x8*)&cb[goff + n * 512];
      buv[n] = *(const bf16x8*)&cb[uoff + n * 512];
    }
    __builtin_amdgcn_s_setprio(1);
#pragma unroll
    for (int m = 0; m < 2; ++m)
#pragma unroll
      for (int n = 0; n < 2; ++n) {
        ag[m][n] = __builtin_amdgcn_mfma_f32_16x16x32_bf16(af[m], bgv[n], ag[m][n], 0, 0, 0);
        au[m][n] = __builtin_amdgcn_mfma_f32_16x16x32_bf16(af[m], buv[n], au[m][n], 0, 0, 0);
      }
    __builtin_amdgcn_s_setprio(0);
    cbuf = nbuf;
  }

#pragma unroll
  for (int m = 0; m < 2; ++m) {
    const int row = row0 + wr * 32 + m * 16 + lg * 4;
#pragma unroll
    for (int n = 0; n < 2; ++n) {
      const int col = col0 + wc * 32 + n * 16 + l15;
#pragma unroll
      for (int r = 0; r < 4; ++r) {
        const float g = ag[m][n][r];
        const float u = au[m][n][r];
        C16[(size_t)(row + r) * N + col] = f2bf(g / (1.0f + __expf(-g)) * u);
      }
    }
  }
}

// ---------------- attention: flash-style, no-max exp2 softmax (Q pre-scaled), ----------------
// denominator via MFMA row-sum; P->bf16 via v_cvt_pk; causal load-balanced grid.
__global__ __launch_bounds__(256) void attn_k(const u16* __restrict__ Q,
                                              const u16* __restrict__ Kc,
                                              const u16* __restrict__ Vt,
                                              u16* __restrict__ O) {
  __shared__ u16 P_lds[4][32][72];
  const int bid = blockIdx.x;           // 512 blocks
  const int bh = bid & 31;
  const int jj = bid >> 5;              // 0..15
  const int qi = (bid < 256) ? jj : 23 - jj;
  const int q0 = qi << 7;
  const int lane = threadIdx.x & 63;
  const int w = threadIdx.x >> 6;
  const int l15 = lane & 15, lg = lane >> 4;
  const int qbase = q0 + w * 32;

  bf16x8 qf[2][2];
#pragma unroll
  for (int am = 0; am < 2; ++am)
#pragma unroll
    for (int ks = 0; ks < 2; ++ks)
      qf[am][ks] = *(const bf16x8*)&Q[((size_t)bh * TT + qbase + am * 16 + l15) * HDD + ks * 32 + lg * 8];

  bf16x8 ones;
#pragma unroll
  for (int i = 0; i < 8; ++i) ones[i] = (short)0x3F80;  // bf16 1.0

  f32x4 oacc[2][4] = {};
  f32x4 lacc[2] = {};

  const int ntile = (q0 + 128) >> 6;
  for (int kt = 0; kt < ntile; ++kt) {
    const int k0 = kt << 6;
    f32x4 s[2][4];
    bf16x8 kf0[4], kf1[4];
#pragma unroll
    for (int an = 0; an < 4; ++an) {
      kf0[an] = *(const bf16x8*)&Kc[((size_t)bh * TT + k0 + an * 16 + l15) * HDD + lg * 8];
      kf1[an] = *(const bf16x8*)&Kc[((size_t)bh * TT + k0 + an * 16 + l15) * HDD + 32 + lg * 8];
    }
    __builtin_amdgcn_s_setprio(1);
#pragma unroll
    for (int an = 0; an < 4; ++an) {
#pragma unroll
      for (int am = 0; am < 2; ++am) {
        f32x4 z = {0.0f, 0.0f, 0.0f, 0.0f};
        z = __builtin_amdgcn_mfma_f32_16x16x32_bf16(qf[am][0], kf0[an], z, 0, 0, 0);
        s[am][an] = __builtin_amdgcn_mfma_f32_16x16x32_bf16(qf[am][1], kf1[an], z, 0, 0, 0);
      }
    }
    __builtin_amdgcn_s_setprio(0);
    // causal mask + 2^x (Q pre-scaled by 0.125*log2e; scores bounded, f32-safe)
    const bool diag = (k0 + 64) > q0;
#pragma unroll
    for (int am = 0; am < 2; ++am)
#pragma unroll
      for (int an = 0; an < 4; ++an)
#pragma unroll
        for (int r = 0; r < 4; ++r) {
          float v = s[am][an][r];
          if (diag) {
            const int qrow = qbase + am * 16 + lg * 4 + r;
            const int kcol = k0 + an * 16 + l15;
            if (kcol > qrow) v = -1e30f;
          }
          float p;
          asm("v_exp_f32 %0, %1" : "=v"(p) : "v"(v));
          s[am][an][r] = p;
        }
    // P -> LDS via packed bf16 conversion, then PV + l-sum MFMA
#pragma unroll
    for (int am = 0; am < 2; ++am)
#pragma unroll
      for (int an = 0; an < 4; ++an)
#pragma unroll
        for (int rp = 0; rp < 2; ++rp) {
          u32 pk;
          asm("v_cvt_pk_bf16_f32 %0, %1, %2"
              : "=v"(pk) : "v"(s[am][an][2 * rp]), "v"(s[am][an][2 * rp + 1]));
          const int rowb = am * 16 + lg * 4 + 2 * rp;
          P_lds[w][rowb][an * 16 + l15] = (u16)pk;
          P_lds[w][rowb + 1][an * 16 + l15] = (u16)(pk >> 16);
        }
#pragma unroll
    for (int ks = 0; ks < 2; ++ks) {
      bf16x8 pf[2];
#pragma unroll
      for (int am = 0; am < 2; ++am)
        pf[am] = *(const bf16x8*)&P_lds[w][am * 16 + l15][ks * 32 + lg * 8];
      __builtin_amdgcn_s_setprio(1);
#pragma unroll
      for (int dn = 0; dn < 4; ++dn) {
        const bf16x8 vf = *(const bf16x8*)&Vt[((size_t)bh * HDD + dn * 16 + l15) * TT + k0 + ks * 32 + lg * 8];
#pragma unroll
        for (int am = 0; am < 2; ++am)
          oacc[am][dn] = __builtin_amdgcn_mfma_f32_16x16x32_bf16(pf[am], vf, oacc[am][dn], 0, 0, 0);
      }
#pragma unroll
      for (int am = 0; am < 2; ++am)
        lacc[am] = __builtin_amdgcn_mfma_f32_16x16x32_bf16(pf[am], ones, lacc[am], 0, 0, 0);
      __builtin_amdgcn_s_setprio(0);
    }
  }
  const int b = bh >> 4, h = bh & 15;
#pragma unroll
  for (int am = 0; am < 2; ++am)
#pragma unroll
    for (int r = 0; r < 4; ++r) {
      const float il = 1.0f / lacc[am][r];
      const int qrow = qbase + am * 16 + lg * 4 + r;
#pragma unroll
      for (int dn = 0; dn < 4; ++dn)
        O[((size_t)b * TT + qrow) * EE + h * 64 + dn * 16 + l15] = f2bf(oacc[am][dn][r] * il);
    }
}

// ---------------- host ----------------

extern "C" void kernel_launch(void* const* d_in, const int* in_sizes, int n_in,
                              void* d_out, int out_size, void* d_ws, size_t ws_size,
                              hipStream_t stream) {
  const int* idx = (const int*)d_in[0];
  const float* tok_emb = (const float*)d_in[1];
  const float* qkv_w = (const float*)d_in[2];
  const float* proj_w = (const float*)d_in[3];
  const float* w1 = (const float*)d_in[4];
  const float* w2 = (const float*)d_in[5];
  const float* w3 = (const float*)d_in[6];
  const float* norm1_w = (const float*)d_in[7];
  const float* norm2_w = (const float*)d_in[8];
  const float* norm_f_w = (const float*)d_in[9];
  float* out = (float*)d_out;

  char* ws = (char*)d_ws;
  size_t off = 0;
  auto alloc = [&](size_t bytes) -> void* {
    off = (off + 255) & ~(size_t)255;
    void* p = ws + off;
    off += bytes;
    return p;
  };

  const size_t N_TEMB = (size_t)VV * EE;
  const size_t N_QKVW = (size_t)8 * 3 * EE * EE;
  const size_t N_PROJW = (size_t)8 * EE * EE;
  const size_t N_W1 = (size_t)8 * HIDD * EE;
  const size_t N_W3 = (size_t)8 * EE * HIDD;

  u16* tembbf = (u16*)alloc(N_TEMB * 2);
  u16* qkvwbf = (u16*)alloc(N_QKVW * 2);
  u16* projwbf = (u16*)alloc(N_PROJW * 2);
  u16* w1bf = (u16*)alloc(N_W1 * 2);
  u16* w2bf = (u16*)alloc(N_W1 * 2);
  u16* w3bf = (u16*)alloc(N_W3 * 2);
  float* x = (float*)alloc((size_t)MM * EE * 4);
  u16* h1 = (u16*)alloc((size_t)MM * EE * 2);
  u16* hg = (u16*)alloc((size_t)MM * HIDD * 2);
  u16* qb = (u16*)alloc((size_t)2 * NHH * TT * HDD * 2);
  u16* kb = (u16*)alloc((size_t)2 * NHH * TT * HDD * 2);
  u16* vtb = (u16*)alloc((size_t)2 * NHH * TT * HDD * 2);
  u16* attno = (u16*)alloc((size_t)MM * EE * 2);
  float* cosT = (float*)alloc((size_t)TT * 32 * 4);
  float* sinT = (float*)alloc((size_t)TT * 32 * 4);

  auto cast = [&](const float* src, u16* dst, size_t n) {
    const long n4 = (long)(n / 4);
    castbf_k<<<(int)((n4 + 255) / 256), 256, 0, stream>>>(src, dst, n4);
  };
  cast(tok_emb, tembbf, N_TEMB);
  cast(qkv_w, qkvwbf, N_QKVW);
  cast(proj_w, projwbf, N_PROJW);
  cast(w1, w1bf, N_W1);
  cast(w2, w2bf, N_W1);
  cast(w3, w3bf, N_W3);

  ropetab_k<<<TT, 32, 0, stream>>>(cosT, sinT);
  embed_k<<<MM, 256, 0, stream>>>(idx, tok_emb, x);

  for (int l = 0; l < 8; ++l) {
    rmsnorm_k<<<MM, 256, 0, stream>>>(x, norm1_w + l * EE, h1);
    gemm128n<3><<<dim3(24 * 32), 512, 0, stream>>>(h1, qkvwbf + (size_t)l * 3 * EE * EE,
                                                   nullptr, nullptr,
                                                   cosT, sinT, qb, kb, vtb, 3 * EE, EE);
    attn_k<<<dim3(512), 256, 0, stream>>>(qb, kb, vtb, attno);
    gemm128n<0><<<dim3(8 * 32), 512, 0, stream>>>(attno, projwbf + (size_t)l * EE * EE,
                                                  x, x,
                                                  nullptr, nullptr, nullptr, nullptr, nullptr,
                                                  EE, EE);
    rmsnorm_k<<<MM, 256, 0, stream>>>(x, norm2_w + l * EE, h1);
    gemm128d<<<dim3(44 * 32), 512, 0, stream>>>(h1, w1bf + (size_t)l * HIDD * EE,
                                                w2bf + (size_t)l * HIDD * EE,
                                                hg, HIDD, EE);
    gemm128n<0><<<dim3(8 * 32), 512, 0, stream>>>(hg, w3bf + (size_t)l * EE * HIDD,
                                                  x, x,
                                                  nullptr, nullptr, nullptr, nullptr, nullptr,
                                                  EE, HIDD);
  }
  rmsnorm_k<<<MM, 256, 0, stream>>>(x, norm_f_w, h1);
  gemm256p<0><<<dim3(125 * 16), 512, 0, stream>>>(h1, tembbf, out, nullptr, nullptr,
                                                  VV, EE);
}

// Round 16
// 2419.590 us; speedup vs baseline: 1.1522x; 1.0014x over previous
//
#include <hip/hip_runtime.h>

#define GLOBAL_AS __attribute__((address_space(1)))
#define LDS_AS __attribute__((address_space(3)))

typedef unsigned short u16;
typedef unsigned int u32;
typedef __attribute__((ext_vector_type(4))) float f32x4;
typedef __attribute__((ext_vector_type(8))) short bf16x8;

// Model dims
#define TT 2048
#define EE 1024
#define NHH 16
#define HDD 64
#define HIDD 2816
#define VV 32000
#define MM 4096   // B*T

__device__ __forceinline__ u16 f2bf(float f) {
  u32 u = __builtin_bit_cast(u32, f);
  u += 0x7fffu + ((u >> 16) & 1u);
  return (u16)(u >> 16);
}
__device__ __forceinline__ float bf2f(u16 v) {
  return __builtin_bit_cast(float, (u32)v << 16);
}

// ---------------- elementwise / staging kernels ----------------

__global__ __launch_bounds__(256) void castbf_k(const float* __restrict__ in,
                                                u16* __restrict__ o, long n4) {
  const long i = (long)blockIdx.x * 256 + threadIdx.x;
  if (i >= n4) return;
  const float4 v = ((const float4*)in)[i];
  ((uint2*)o)[i] = make_uint2((u32)f2bf(v.x) | ((u32)f2bf(v.y) << 16),
                              (u32)f2bf(v.z) | ((u32)f2bf(v.w) << 16));
}

__global__ void ropetab_k(float* __restrict__ cosT, float* __restrict__ sinT) {
  const int t = blockIdx.x, j = threadIdx.x;  // j in [0,32)
  const float inv = powf(10000.0f, -(float)j * (1.0f / 32.0f));
  const float f = (float)t * inv;
  cosT[t * 32 + j] = cosf(f);
  sinT[t * 32 + j] = sinf(f);
}

__global__ __launch_bounds__(256) void embed_k(const int* __restrict__ idx,
                                               const float* __restrict__ temb,
                                               float* __restrict__ x) {
  const int row = blockIdx.x;
  const int id = idx[row];
  ((float4*)(x + (size_t)row * EE))[threadIdx.x] =
      ((const float4*)(temb + (size_t)id * EE))[threadIdx.x];
}

__global__ __launch_bounds__(256) void rmsnorm_k(const float* __restrict__ x,
                                                 const float* __restrict__ w,
                                                 u16* __restrict__ o) {
  __shared__ float red[4];
  const int row = blockIdx.x, tid = threadIdx.x;
  const float4 v = ((const float4*)(x + (size_t)row * EE))[tid];
  float ss = v.x * v.x + v.y * v.y + v.z * v.z + v.w * v.w;
#pragma unroll
  for (int off = 32; off; off >>= 1) ss += __shfl_xor(ss, off, 64);
  if ((tid & 63) == 0) red[tid >> 6] = ss;
  __syncthreads();
  const float inv = rsqrtf((red[0] + red[1] + red[2] + red[3]) * (1.0f / 1024.0f) + 1e-6f);
  const float4 wv = ((const float4*)w)[tid];
  const u32 lo = (u32)f2bf(v.x * inv * wv.x) | ((u32)f2bf(v.y * inv * wv.y) << 16);
  const u32 hi = (u32)f2bf(v.z * inv * wv.z) | ((u32)f2bf(v.w * inv * wv.w) << 16);
  ((uint2*)(o + (size_t)row * EE))[tid] = make_uint2(lo, hi);
}

// ---------------- GEMM engine: 256x256, BK=64, 4-phase counted-vmcnt dbuf (R5 engine) ----------------
// Used for the logits GEMM only (grid 2000 blocks). Best measured schedule (38% MfmaUtil).
template <int OUTBF>
__global__ __launch_bounds__(512, 2) void gemm256p(const u16* __restrict__ A,
                                                   const u16* __restrict__ Bw,
                                                   float* __restrict__ C,
                                                   u16* __restrict__ C16,
                                                   const u16* __restrict__ G,
                                                   int N, int K) {
  __shared__ u16 lds[2 * 32768];  // 128 KB
  const int t = threadIdx.x;
  const int lane = t & 63;
  const int wid = t >> 6;
  const int wr = wid >> 2;   // 0..1
  const int wc = wid & 3;    // 0..3
  const int l15 = lane & 15, lg = lane >> 4;
  const int bid = blockIdx.x;
  const int row0 = (bid & 15) << 8;
  const int col0 = (bid >> 4) << 8;
  const int NT = K >> 6;

  const int sr = t >> 3;
  const int su8 = (((t & 7) ^ (sr & 7)) << 3);  // pre-swizzled global elem offset
  const int t8 = t << 3;
  const u16* aG[4];
#pragma unroll
  for (int ga = 0; ga < 4; ++ga)
    aG[ga] = A + (size_t)(row0 + ga * 64 + sr) * K + su8;
  const u16* bG[4];
#pragma unroll
  for (int gb = 0; gb < 4; ++gb) {
    const int q = (gb * 2 + (sr >> 5)) & 3;
    const int nh = gb >> 1;
    bG[gb] = Bw + (size_t)(col0 + q * 64 + nh * 32 + (sr & 31)) * K + su8;
  }

  const int u0 = ((lg ^ (l15 & 7)) << 3);          // ks=0 unit
  const int u1 = (((4 | lg) ^ (l15 & 7)) << 3);    // ks=1 unit
  const int arow = (wr * 128 + l15) << 6;          // + m*1024
  const int brow = 16384 + ((wc * 32 + l15) << 6); // + nh*8192 + ni*1024

  f32x4 acc[8][4] = {};

#define STA(nb, ga, k0n)                                                              \
  __builtin_amdgcn_global_load_lds((const GLOBAL_AS void*)(aG[ga] + (k0n)),           \
                                   (LDS_AS void*)((nb) + (ga)*4096 + t8), 16, 0, 0)
#define STB(nb, gb, k0n)                                                              \
  __builtin_amdgcn_global_load_lds((const GLOBAL_AS void*)(bG[gb] + (k0n)),           \
                                   (LDS_AS void*)((nb) + 16384 + (gb)*4096 + t8), 16, 0, 0)

  {
    u16* nb = lds;
    STA(nb, 0, 0); STA(nb, 2, 0);
    STB(nb, 0, 0); STB(nb, 1, 0);
    STB(nb, 2, 0); STB(nb, 3, 0);
    STA(nb, 1, 0); STA(nb, 3, 0);
  }

  bf16x8 af[4][2], bl[2][2], bh[2][2];

  for (int kt = 0; kt < NT; ++kt) {
    const bool st = (kt + 1 < NT);
    const int k0n = (kt + 1) << 6;
    const u16* cb = lds + (kt & 1) * 32768;
    u16* nb = lds + ((kt + 1) & 1) * 32768;

    // ---- phase 0: mh=0, nh=0 ----
    asm volatile("s_waitcnt vmcnt(4)" ::: "memory");
    __builtin_amdgcn_s_barrier();
#pragma unroll
    for (int mi = 0; mi < 4; ++mi) {
      af[mi][0] = *(const bf16x8*)&cb[arow + mi * 1024 + u0];
      af[mi][1] = *(const bf16x8*)&cb[arow + mi * 1024 + u1];
    }
#pragma unroll
    for (int ni = 0; ni < 2; ++ni) {
      bl[ni][0] = *(const bf16x8*)&cb[brow + ni * 1024 + u0];
      bl[ni][1] = *(const bf16x8*)&cb[brow + ni * 1024 + u1];
    }
    if (st) { STA(nb, 0, k0n); STA(nb, 2, k0n); }
    __builtin_amdgcn_s_setprio(1);
#pragma unroll
    for (int mi = 0; mi < 4; ++mi)
#pragma unroll
      for (int ni = 0; ni < 2; ++ni) {
        acc[mi][ni] = __builtin_amdgcn_mfma_f32_16x16x32_bf16(af[mi][0], bl[ni][0], acc[mi][ni], 0, 0, 0);
        acc[mi][ni] = __builtin_amdgcn_mfma_f32_16x16x32_bf16(af[mi][1], bl[ni][1], acc[mi][ni], 0, 0, 0);
      }
    __builtin_amdgcn_s_setprio(0);

    // ---- phase 1: mh=0, nh=1 ----
    if (st) { asm volatile("s_waitcnt vmcnt(4)" ::: "memory"); }
    else    { asm volatile("s_waitcnt vmcnt(2)" ::: "memory"); }
    __builtin_amdgcn_s_barrier();
#pragma unroll
    for (int ni = 0; ni < 2; ++ni) {
      bh[ni][0] = *(const bf16x8*)&cb[brow + 8192 + ni * 1024 + u0];
      bh[ni][1] = *(const bf16x8*)&cb[brow + 8192 + ni * 1024 + u1];
    }
    if (st) { STB(nb, 0, k0n); STB(nb, 1, k0n); }
    __builtin_amdgcn_s_setprio(1);
#pragma unroll
    for (int mi = 0; mi < 4; ++mi)
#pragma unroll
      for (int ni = 0; ni < 2; ++ni) {
        acc[mi][2 + ni] = __builtin_amdgcn_mfma_f32_16x16x32_bf16(af[mi][0], bh[ni][0], acc[mi][2 + ni], 0, 0, 0);
        acc[mi][2 + ni] = __builtin_amdgcn_mfma_f32_16x16x32_bf16(af[mi][1], bh[ni][1], acc[mi][2 + ni], 0, 0, 0);
      }
    __builtin_amdgcn_s_setprio(0);

    // ---- phase 2: mh=1, nh=1 ----
    if (st) { asm volatile("s_waitcnt vmcnt(4)" ::: "memory"); }
    else    { asm volatile("s_waitcnt vmcnt(0)" ::: "memory"); }
    __builtin_amdgcn_s_barrier();
#pragma unroll
    for (int mi = 0; mi < 4; ++mi) {
      af[mi][0] = *(const bf16x8*)&cb[arow + (4 + mi) * 1024 + u0];
      af[mi][1] = *(const bf16x8*)&cb[arow + (4 + mi) * 1024 + u1];
    }
    if (st) { STB(nb, 2, k0n); STB(nb, 3, k0n); }
    __builtin_amdgcn_s_setprio(1);
#pragma unroll
    for (int mi = 0; mi < 4; ++mi)
#pragma unroll
      for (int ni = 0; ni < 2; ++ni) {
        acc[4 + mi][2 + ni] = __builtin_amdgcn_mfma_f32_16x16x32_bf16(af[mi][0], bh[ni][0], acc[4 + mi][2 + ni], 0, 0, 0);
        acc[4 + mi][2 + ni] = __builtin_amdgcn_mfma_f32_16x16x32_bf16(af[mi][1], bh[ni][1], acc[4 + mi][2 + ni], 0, 0, 0);
      }
    __builtin_amdgcn_s_setprio(0);

    // ---- phase 3: mh=1, nh=0 (no new reads) ----
    if (st) { STA(nb, 1, k0n); STA(nb, 3, k0n); }
    __builtin_amdgcn_s_setprio(1);
#pragma unroll
    for (int mi = 0; mi < 4; ++mi)
#pragma unroll
      for (int ni = 0; ni < 2; ++ni) {
        acc[4 + mi][ni] = __builtin_amdgcn_mfma_f32_16x16x32_bf16(af[mi][0], bl[ni][0], acc[4 + mi][ni], 0, 0, 0);
        acc[4 + mi][ni] = __builtin_amdgcn_mfma_f32_16x16x32_bf16(af[mi][1], bl[ni][1], acc[4 + mi][ni], 0, 0, 0);
      }
    __builtin_amdgcn_s_setprio(0);
  }
#undef STA
#undef STB

#pragma unroll
  for (int m = 0; m < 8; ++m) {
    const int row = row0 + wr * 128 + m * 16 + lg * 4;
#pragma unroll
    for (int n = 0; n < 4; ++n) {
      const int col = col0 + wc * 64 + n * 16 + l15;
#pragma unroll
      for (int r = 0; r < 4; ++r) {
        const size_t o = (size_t)(row + r) * N + col;
        if (OUTBF == 0) {
          C[o] = acc[m][n][r];
        } else if (OUTBF == 1) {
          C16[o] = f2bf(acc[m][n][r]);
        } else {
          const float g = bf2f(G[o]);
          C16[o] = f2bf(g / (1.0f + __expf(-g)) * acc[m][n][r]);
        }
      }
    }
  }
}

// ---------------- GEMM engine: 128x128, 8 waves (wave-tile 32x64), ring, epilogues ----------------
// Proven R8 ring schedule: 4-buf LDS ring, depth-3 prefetch, counted vmcnt 4/2/0.
// OUTBF: 0 f32 C = acc + R ; 3 rope-split (Q pre-scaled by 0.125*log2e for exp2 softmax).
template <int OUTBF>
__global__ __launch_bounds__(512, 2) void gemm128n(const u16* __restrict__ A,
                                                   const u16* __restrict__ Bw,
                                                   float* __restrict__ C,
                                                   const float* __restrict__ R,
                                                   const float* __restrict__ cosT,
                                                   const float* __restrict__ sinT,
                                                   u16* __restrict__ Qb,
                                                   u16* __restrict__ Kb,
                                                   u16* __restrict__ Vtb,
                                                   int N, int K) {
  __shared__ u16 lds[4 * 8192];  // 64 KB: 4 buffers x (A 128x32 | B 128x32)
  const int t = threadIdx.x;
  const int lane = t & 63;
  const int wid = t >> 6;
  const int wr = wid & 3;    // 0..3 : 32-row group
  const int wc = wid >> 2;   // 0..1 : 64-col group
  const int l15 = lane & 15, lg = lane >> 4;
  const int bid = blockIdx.x;
  const int row0 = (bid & 31) << 7;
  const int col0 = (bid >> 5) << 7;
  const int NT = K >> 5;

  const int rA = t >> 2;  // 0..127
  const int usw = (((t & 3) ^ ((t >> 3) & 3)) << 3);
  const u16* sA = A + (size_t)(row0 + rA) * K + usw;
  const u16* sB = Bw + (size_t)(col0 + rA) * K + usw;
  const int dst = t << 3;  // 0..4095

  const int e8 = ((lg ^ ((l15 >> 1) & 3)) << 3);
  const int aoff = (wr * 32 + l15) * 32 + e8;
  const int boff = 4096 + (wc * 64 + l15) * 32 + e8;

  f32x4 acc[2][4] = {};

  auto stage = [&](int kt) {
    u16* base = &lds[(kt & 3) * 8192];
    const size_t ko = (size_t)kt * 32;
    __builtin_amdgcn_global_load_lds((const GLOBAL_AS void*)(sA + ko),
                                     (LDS_AS void*)(base + dst), 16, 0, 0);
    __builtin_amdgcn_global_load_lds((const GLOBAL_AS void*)(sB + ko),
                                     (LDS_AS void*)(base + 4096 + dst), 16, 0, 0);
  };

  stage(0);
  stage(1);
  stage(2);

  for (int kt = 0; kt < NT; ++kt) {
    const int rem = NT - 1 - kt;
    if (rem >= 2) {
      asm volatile("s_waitcnt vmcnt(4)" ::: "memory");
    } else if (rem == 1) {
      asm volatile("s_waitcnt vmcnt(2)" ::: "memory");
    } else {
      asm volatile("s_waitcnt vmcnt(0)" ::: "memory");
    }
    __builtin_amdgcn_s_barrier();
    if (kt + 3 < NT) stage(kt + 3);
    const u16* base = &lds[(kt & 3) * 8192];
    bf16x8 af[2], bfv[4];
#pragma unroll
    for (int m = 0; m < 2; ++m) af[m] = *(const bf16x8*)&base[aoff + m * 512];
#pragma unroll
    for (int n = 0; n < 4; ++n) bfv[n] = *(const bf16x8*)&base[boff + n * 512];
    __builtin_amdgcn_s_setprio(1);
#pragma unroll
    for (int m = 0; m < 2; ++m)
#pragma unroll
      for (int n = 0; n < 4; ++n)
        acc[m][n] = __builtin_amdgcn_mfma_f32_16x16x32_bf16(af[m], bfv[n], acc[m][n], 0, 0, 0);
    __builtin_amdgcn_s_setprio(0);
  }

  if (OUTBF == 3) {
    // fused RoPE + QKV split. Tile entirely in Q (col0<1024), K, or V region.
    const int reg = col0 >> 10;
    const int fb = col0 & 1023;
#pragma unroll
    for (int m = 0; m < 2; ++m) {
      const int row = row0 + wr * 32 + m * 16 + lg * 4;
      const int b = row >> 11, tbase = row & 2047;
      if (reg < 2) {
        u16* dstp = (reg == 0) ? Qb : Kb;
        // Q pre-scaled by 0.125*log2(e) so attn softmax uses raw v_exp_f32 (2^x).
        const float qs = (reg == 0) ? 0.18033688011112042f : 1.0f;
#pragma unroll
        for (int n = 0; n < 2; ++n) {
          const int f = fb + wc * 64 + n * 16 + l15;
          const int h = f >> 6, j = f & 63;  // j < 32
#pragma unroll
          for (int r = 0; r < 4; ++r) {
            const int tt = tbase + r;
            const float c = cosT[tt * 32 + j], s = sinT[tt * 32 + j];
            const float x1 = acc[m][n][r], x2 = acc[m][n | 2][r];
            const size_t ro = ((size_t)(b * NHH + h) * TT + tt) * HDD + j;
            dstp[ro] = f2bf((x1 * c - x2 * s) * qs);
            dstp[ro + 32] = f2bf((x1 * s + x2 * c) * qs);
          }
        }
      } else {
#pragma unroll
        for (int n = 0; n < 4; ++n) {
          const int f = fb + wc * 64 + n * 16 + l15;
          const int h = f >> 6, j = f & 63;
          ushort4 pk;
          pk.x = f2bf(acc[m][n][0]);
          pk.y = f2bf(acc[m][n][1]);
          pk.z = f2bf(acc[m][n][2]);
          pk.w = f2bf(acc[m][n][3]);
          *(ushort4*)&Vtb[((size_t)(b * NHH + h) * HDD + j) * TT + tbase] = pk;
        }
      }
    }
    return;
  }

#pragma unroll
  for (int m = 0; m < 2; ++m) {
    const int row = row0 + wr * 32 + m * 16 + lg * 4;
#pragma unroll
    for (int n = 0; n < 4; ++n) {
      const int col = col0 + wc * 64 + n * 16 + l15;
#pragma unroll
      for (int r = 0; r < 4; ++r) {
        const size_t o = (size_t)(row + r) * N + col;
        C[o] = acc[m][n][r] + R[o];
      }
    }
  }
}

// ---------------- GEMM engine: dual-B 128x64 (g=A*W1^T, u=A*W2^T, silu fused), ----------------
// Ring: 3 bufs x 16KB, depth-2, counted vmcnt 2/0. A staged by all 8 waves,
// Bg by waves 0-3, Bu by waves 4-7 (2 glds/wave/stage -> uniform vmcnt math).
__global__ __launch_bounds__(512, 2) void gemm128d(const u16* __restrict__ A,
                                                   const u16* __restrict__ Bg,
                                                   const u16* __restrict__ Bu,
                                                   u16* __restrict__ C16,
                                                   int N, int K) {
  __shared__ u16 lds[3 * 8192];  // 48 KB: 3 bufs x (A 4096 | Bg 2048 | Bu 2048) u16
  const int t = threadIdx.x;
  const int lane = t & 63;
  const int wid = t >> 6;
  const int wr = wid & 3;    // 32-row group
  const int wc = wid >> 2;   // 0..1 : 32-col group
  const int l15 = lane & 15, lg = lane >> 4;
  const int bid = blockIdx.x;
  const int row0 = (bid & 31) << 7;   // 32 row tiles of 128
  const int col0 = (bid >> 5) << 6;   // 64-col tiles
  const int NT = K >> 5;

  const int rA = t >> 2;              // 0..127
  const int usw = (((t & 3) ^ ((t >> 3) & 3)) << 3);
  const u16* sA = A + (size_t)(row0 + rA) * K + usw;
  const int tb = t & 255;
  const int rB = tb >> 2;             // 0..63
  const int uswB = (((tb & 3) ^ ((tb >> 3) & 3)) << 3);
  const u16* sB = ((wid < 4) ? Bg : Bu) + (size_t)(col0 + rB) * K + uswB;
  const int dstA = t << 3;
  const int dstB = 4096 + ((wid < 4) ? 0 : 2048) + (tb << 3);

  const int e8 = ((lg ^ ((l15 >> 1) & 3)) << 3);
  const int aoff = (wr * 32 + l15) * 32 + e8;
  const int goff = 4096 + (wc * 32 + l15) * 32 + e8;
  const int uoff = 6144 + (wc * 32 + l15) * 32 + e8;

  f32x4 ag[2][2] = {}, au[2][2] = {};

  auto stage = [&](int kt, int buf) {
    u16* b = &lds[buf * 8192];
    const size_t ko = (size_t)kt * 32;
    __builtin_amdgcn_global_load_lds((const GLOBAL_AS void*)(sA + ko),
                                     (LDS_AS void*)(b + dstA), 16, 0, 0);
    __builtin_amdgcn_global_load_lds((const GLOBAL_AS void*)(sB + ko),
                                     (LDS_AS void*)(b + dstB), 16, 0, 0);
  };

  stage(0, 0);
  stage(1, 1);

  int cbuf = 0;
  for (int kt = 0; kt < NT; ++kt) {
    if (kt + 1 < NT) {
      asm volatile("s_waitcnt vmcnt(2)" ::: "memory");
    } else {
      asm volatile("s_waitcnt vmcnt(0)" ::: "memory");
    }
    __builtin_amdgcn_s_barrier();
    const int nbuf = (cbuf == 2) ? 0 : cbuf + 1;
    const int sbuf = (nbuf == 2) ? 0 : nbuf + 1;
    if (kt + 2 < NT) stage(kt + 2, sbuf);
    const u16* cb = &lds[cbuf * 8192];
    bf16x8 af[2], bgv[2], buv[2];
#pragma unroll
    for (int m = 0; m < 2; ++m) af[m] = *(const bf16x8*)&cb[aoff + m * 512];
#pragma unroll
    for (int n = 0; n < 2; ++n) {
      bgv[n] = *(const bf16x8*)&cb[goff + n * 512];
      buv[n] = *(const bf16x8*)&cb[uoff + n * 512];
    }
    __builtin_amdgcn_s_setprio(1);
#pragma unroll
    for (int m = 0; m < 2; ++m)
#pragma unroll
      for (int n = 0; n < 2; ++n) {
        ag[m][n] = __builtin_amdgcn_mfma_f32_16x16x32_bf16(af[m], bgv[n], ag[m][n], 0, 0, 0);
        au[m][n] = __builtin_amdgcn_mfma_f32_16x16x32_bf16(af[m], buv[n], au[m][n], 0, 0, 0);
      }
    __builtin_amdgcn_s_setprio(0);
    cbuf = nbuf;
  }

#pragma unroll
  for (int m = 0; m < 2; ++m) {
    const int row = row0 + wr * 32 + m * 16 + lg * 4;
#pragma unroll
    for (int n = 0; n < 2; ++n) {
      const int col = col0 + wc * 32 + n * 16 + l15;
#pragma unroll
      for (int r = 0; r < 4; ++r) {
        const float g = ag[m][n][r];
        const float u = au[m][n][r];
        C16[(size_t)(row + r) * N + col] = f2bf(g / (1.0f + __expf(-g)) * u);
      }
    }
  }
}

// ---------------- attention: flash-style, no-max exp2 softmax (Q pre-scaled), ----------------
// denominator via MFMA row-sum; P->bf16 via v_cvt_pk; causal load-balanced grid.
__global__ __launch_bounds__(256) void attn_k(const u16* __restrict__ Q,
                                              const u16* __restrict__ Kc,
                                              const u16* __restrict__ Vt,
                                              u16* __restrict__ O) {
  __shared__ u16 P_lds[4][32][72];
  const int bid = blockIdx.x;           // 512 blocks
  const int bh = bid & 31;
  const int jj = bid >> 5;              // 0..15
  const int qi = (bid < 256) ? jj : 23 - jj;
  const int q0 = qi << 7;
  const int lane = threadIdx.x & 63;
  const int w = threadIdx.x >> 6;
  const int l15 = lane & 15, lg = lane >> 4;
  const int qbase = q0 + w * 32;

  bf16x8 qf[2][2];
#pragma unroll
  for (int am = 0; am < 2; ++am)
#pragma unroll
    for (int ks = 0; ks < 2; ++ks)
      qf[am][ks] = *(const bf16x8*)&Q[((size_t)bh * TT + qbase + am * 16 + l15) * HDD + ks * 32 + lg * 8];

  bf16x8 ones;
#pragma unroll
  for (int i = 0; i < 8; ++i) ones[i] = (short)0x3F80;  // bf16 1.0

  f32x4 oacc[2][4] = {};
  f32x4 lacc[2] = {};

  const int ntile = (q0 + 128) >> 6;
  for (int kt = 0; kt < ntile; ++kt) {
    const int k0 = kt << 6;
    f32x4 s[2][4];
    bf16x8 kf0[4], kf1[4];
#pragma unroll
    for (int an = 0; an < 4; ++an) {
      kf0[an] = *(const bf16x8*)&Kc[((size_t)bh * TT + k0 + an * 16 + l15) * HDD + lg * 8];
      kf1[an] = *(const bf16x8*)&Kc[((size_t)bh * TT + k0 + an * 16 + l15) * HDD + 32 + lg * 8];
    }
    __builtin_amdgcn_s_setprio(1);
#pragma unroll
    for (int an = 0; an < 4; ++an) {
#pragma unroll
      for (int am = 0; am < 2; ++am) {
        f32x4 z = {0.0f, 0.0f, 0.0f, 0.0f};
        z = __builtin_amdgcn_mfma_f32_16x16x32_bf16(qf[am][0], kf0[an], z, 0, 0, 0);
        s[am][an] = __builtin_amdgcn_mfma_f32_16x16x32_bf16(qf[am][1], kf1[an], z, 0, 0, 0);
      }
    }
    __builtin_amdgcn_s_setprio(0);
    // causal mask + 2^x (Q pre-scaled by 0.125*log2e; scores bounded, f32-safe)
    const bool diag = (k0 + 64) > q0;
#pragma unroll
    for (int am = 0; am < 2; ++am)
#pragma unroll
      for (int an = 0; an < 4; ++an)
#pragma unroll
        for (int r = 0; r < 4; ++r) {
          float v = s[am][an][r];
          if (diag) {
            const int qrow = qbase + am * 16 + lg * 4 + r;
            const int kcol = k0 + an * 16 + l15;
            if (kcol > qrow) v = -1e30f;
          }
          float p;
          asm("v_exp_f32 %0, %1" : "=v"(p) : "v"(v));
          s[am][an][r] = p;
        }
    // P -> LDS via packed bf16 conversion, then PV + l-sum MFMA
#pragma unroll
    for (int am = 0; am < 2; ++am)
#pragma unroll
      for (int an = 0; an < 4; ++an)
#pragma unroll
        for (int rp = 0; rp < 2; ++rp) {
          u32 pk;
          asm("v_cvt_pk_bf16_f32 %0, %1, %2"
              : "=v"(pk) : "v"(s[am][an][2 * rp]), "v"(s[am][an][2 * rp + 1]));
          const int rowb = am * 16 + lg * 4 + 2 * rp;
          P_lds[w][rowb][an * 16 + l15] = (u16)pk;
          P_lds[w][rowb + 1][an * 16 + l15] = (u16)(pk >> 16);
        }
#pragma unroll
    for (int ks = 0; ks < 2; ++ks) {
      bf16x8 pf[2];
#pragma unroll
      for (int am = 0; am < 2; ++am)
        pf[am] = *(const bf16x8*)&P_lds[w][am * 16 + l15][ks * 32 + lg * 8];
      __builtin_amdgcn_s_setprio(1);
#pragma unroll
      for (int dn = 0; dn < 4; ++dn) {
        const bf16x8 vf = *(const bf16x8*)&Vt[((size_t)bh * HDD + dn * 16 + l15) * TT + k0 + ks * 32 + lg * 8];
#pragma unroll
        for (int am = 0; am < 2; ++am)
          oacc[am][dn] = __builtin_amdgcn_mfma_f32_16x16x32_bf16(pf[am], vf, oacc[am][dn], 0, 0, 0);
      }
#pragma unroll
      for (int am = 0; am < 2; ++am)
        lacc[am] = __builtin_amdgcn_mfma_f32_16x16x32_bf16(pf[am], ones, lacc[am], 0, 0, 0);
      __builtin_amdgcn_s_setprio(0);
    }
  }
  const int b = bh >> 4, h = bh & 15;
#pragma unroll
  for (int am = 0; am < 2; ++am)
#pragma unroll
    for (int r = 0; r < 4; ++r) {
      const float il = 1.0f / lacc[am][r];
      const int qrow = qbase + am * 16 + lg * 4 + r;
#pragma unroll
      for (int dn = 0; dn < 4; ++dn)
        O[((size_t)b * TT + qrow) * EE + h * 64 + dn * 16 + l15] = f2bf(oacc[am][dn][r] * il);
    }
}

// ---------------- host ----------------

extern "C" void kernel_launch(void* const* d_in, const int* in_sizes, int n_in,
                              void* d_out, int out_size, void* d_ws, size_t ws_size,
                              hipStream_t stream) {
  const int* idx = (const int*)d_in[0];
  const float* tok_emb = (const float*)d_in[1];
  const float* qkv_w = (const float*)d_in[2];
  const float* proj_w = (const float*)d_in[3];
  const float* w1 = (const float*)d_in[4];
  const float* w2 = (const float*)d_in[5];
  const float* w3 = (const float*)d_in[6];
  const float* norm1_w = (const float*)d_in[7];
  const float* norm2_w = (const float*)d_in[8];
  const float* norm_f_w = (const float*)d_in[9];
  float* out = (float*)d_out;

  char* ws = (char*)d_ws;
  size_t off = 0;
  auto alloc = [&](size_t bytes) -> void* {
    off = (off + 255) & ~(size_t)255;
    void* p = ws + off;
    off += bytes;
    return p;
  };

  const size_t N_TEMB = (size_t)VV * EE;
  const size_t N_QKVW = (size_t)8 * 3 * EE * EE;
  const size_t N_PROJW = (size_t)8 * EE * EE;
  const size_t N_W1 = (size_t)8 * HIDD * EE;
  const size_t N_W3 = (size_t)8 * EE * HIDD;

  u16* tembbf = (u16*)alloc(N_TEMB * 2);
  u16* qkvwbf = (u16*)alloc(N_QKVW * 2);
  u16* projwbf = (u16*)alloc(N_PROJW * 2);
  u16* w1bf = (u16*)alloc(N_W1 * 2);
  u16* w2bf = (u16*)alloc(N_W1 * 2);
  u16* w3bf = (u16*)alloc(N_W3 * 2);
  float* x = (float*)alloc((size_t)MM * EE * 4);
  u16* h1 = (u16*)alloc((size_t)MM * EE * 2);
  u16* hg = (u16*)alloc((size_t)MM * HIDD * 2);
  u16* qb = (u16*)alloc((size_t)2 * NHH * TT * HDD * 2);
  u16* kb = (u16*)alloc((size_t)2 * NHH * TT * HDD * 2);
  u16* vtb = (u16*)alloc((size_t)2 * NHH * TT * HDD * 2);
  u16* attno = (u16*)alloc((size_t)MM * EE * 2);
  float* cosT = (float*)alloc((size_t)TT * 32 * 4);
  float* sinT = (float*)alloc((size_t)TT * 32 * 4);

  auto cast = [&](const float* src, u16* dst, size_t n) {
    const long n4 = (long)(n / 4);
    castbf_k<<<(int)((n4 + 255) / 256), 256, 0, stream>>>(src, dst, n4);
  };
  cast(tok_emb, tembbf, N_TEMB);
  cast(qkv_w, qkvwbf, N_QKVW);
  cast(proj_w, projwbf, N_PROJW);
  cast(w1, w1bf, N_W1);
  cast(w2, w2bf, N_W1);
  cast(w3, w3bf, N_W3);

  ropetab_k<<<TT, 32, 0, stream>>>(cosT, sinT);
  embed_k<<<MM, 256, 0, stream>>>(idx, tok_emb, x);

  for (int l = 0; l < 8; ++l) {
    rmsnorm_k<<<MM, 256, 0, stream>>>(x, norm1_w + l * EE, h1);
    gemm128n<3><<<dim3(24 * 32), 512, 0, stream>>>(h1, qkvwbf + (size_t)l * 3 * EE * EE,
                                                   nullptr, nullptr,
                                                   cosT, sinT, qb, kb, vtb, 3 * EE, EE);
    attn_k<<<dim3(512), 256, 0, stream>>>(qb, kb, vtb, attno);
    gemm128n<0><<<dim3(8 * 32), 512, 0, stream>>>(attno, projwbf + (size_t)l * EE * EE,
                                                  x, x,
                                                  nullptr, nullptr, nullptr, nullptr, nullptr,
                                                  EE, EE);
    rmsnorm_k<<<MM, 256, 0, stream>>>(x, norm2_w + l * EE, h1);
    gemm128d<<<dim3(44 * 32), 512, 0, stream>>>(h1, w1bf + (size_t)l * HIDD * EE,
                                                w2bf + (size_t)l * HIDD * EE,
                                                hg, HIDD, EE);
    gemm128n<0><<<dim3(8 * 32), 512, 0, stream>>>(hg, w3bf + (size_t)l * EE * HIDD,
                                                  x, x,
                                                  nullptr, nullptr, nullptr, nullptr, nullptr,
                                                  EE, HIDD);
  }
  rmsnorm_k<<<MM, 256, 0, stream>>>(x, norm_f_w, h1);
  gemm256p<0><<<dim3(125 * 16), 512, 0, stream>>>(h1, tembbf, out, nullptr, nullptr,
                                                  VV, EE);
}